// Round 5
// baseline (619.931 us; speedup 1.0000x reference)
//
#include <hip/hip_runtime.h>
#include <stdint.h>
#include <stddef.h>

// ---------------------------------------------------------------------------
// CSTreeLSTM on gfx950. Levels 1,16,256,4096,65536 (x offsets 0,1,17,273,4369).
// Round 13: leaf fp32-x fusion redone with T14 issue-early/write-late:
// k_level_f32 stages A from fp32 x via reg prefetch (issued one K-tile ahead,
// counted vmcnt(8) leaves them in flight across compute), cvt_pk + swizzled
// ds_write at tile top. Upper levels keep round-10 bf16 k_level verbatim
// (2-phase, T2 swizzle, conflicts=0). k_conv_x converts upper 4369 rows only
// (215MB -> 13MB). k_root_tail fusion retained. Epilogue trims retained.
// ---------------------------------------------------------------------------

typedef __bf16 bf16x8 __attribute__((ext_vector_type(8)));
typedef float  f32x4  __attribute__((ext_vector_type(4)));
typedef unsigned short u16x8 __attribute__((ext_vector_type(8)));
typedef void __attribute__((address_space(3))) lds_void_t;
typedef void __attribute__((address_space(1))) gbl_void_t;

__device__ __forceinline__ uint16_t f2bf(float f) {
  union { __bf16 b; uint16_t u; } v;
  v.b = (__bf16)f;              // RTNE, compiler emits v_cvt_pk_bf16_f32
  return v.u;
}
__device__ __forceinline__ float bf2f(uint16_t u) {
  union { uint32_t u; float f; } v; v.u = (uint32_t)u << 16;
  return v.f;
}
// native v_rcp_f32 (~1 ulp) -- error budget is huge
__device__ __forceinline__ float sig_(float x) {
  return __builtin_amdgcn_rcpf(1.0f + __expf(-x));
}
// tanh(x) = 2/(1+exp(-2x)) - 1 : mul+exp+add+rcp+fma, no clamp, inf-safe
__device__ __forceinline__ float tanh_(float x) {
  return __builtin_fmaf(2.f,
      __builtin_amdgcn_rcpf(1.f + __expf(-2.f * x)), -1.f);
}

// ---- converts --------------------------------------------------------------
__global__ void k_conv_x(const float4* __restrict__ src,
                         ushort4* __restrict__ dst, long n4) {
  long i = blockIdx.x * (long)blockDim.x + threadIdx.x;
  long stride = (long)gridDim.x * blockDim.x;
  for (; i < n4; i += stride) {
    float4 v = src[i];
    ushort4 r;
    r.x = f2bf(v.x); r.y = f2bf(v.y); r.z = f2bf(v.z); r.w = f2bf(v.w);
    dst[i] = r;
  }
}
__global__ void k_conv_w(const float4* __restrict__ w0,
                         const float4* __restrict__ w1,
                         const float4* __restrict__ w2,
                         const float4* __restrict__ w3,
                         ushort4* __restrict__ dst) {
  const long per4 = (long)512 * 1024 / 4;
  long i = blockIdx.x * (long)blockDim.x + threadIdx.x;
  long stride = (long)gridDim.x * blockDim.x;
  for (; i < 4 * per4; i += stride) {
    long seg = i / per4, off2 = i - seg * per4;
    const float4* s = (seg == 0) ? w0 : (seg == 1) ? w1 : (seg == 2) ? w2 : w3;
    float4 v = s[off2];
    ushort4 r;
    r.x = f2bf(v.x); r.y = f2bf(v.y); r.z = f2bf(v.z); r.w = f2bf(v.w);
    dst[i] = r;
  }
}

#define BM 128
#define BN 128
#define BK 32

// ---- plain bf16 GEMM (FxAll only, cold path, 140 blocks) -------------------
__global__ __launch_bounds__(256)
void k_gemm_bt(const uint16_t* __restrict__ A, int lda,
               const uint16_t* __restrict__ B, int ldb,
               float* __restrict__ C, int ldc, int K) {
  __shared__ uint16_t As[BM * BK];
  __shared__ uint16_t Bs[BN * BK];
  const int tid = threadIdx.x, lane = tid & 63, wave = tid >> 6;
  const int lrow = lane & 15, quad = lane >> 4;
  const int wm = (wave >> 1) * 64, wn = (wave & 1) * 64;
  const long tm = blockIdx.x, tn = blockIdx.y;
  f32x4 acc[4][4] = {};
  const int srow = lane >> 2, scol = (lane & 3) * 8;
  for (int k0 = 0; k0 < K; k0 += BK) {
#pragma unroll
    for (int i = 0; i < 2; ++i) {
      int row = i * 64 + wave * 16 + srow;
      const uint16_t* gp = A + (tm * BM + row) * (long)lda + k0 + scol;
      __builtin_amdgcn_global_load_lds((gbl_void_t*)(uintptr_t)gp,
          (lds_void_t*)&As[i * 2048 + wave * 512], 16, 0, 0);
    }
#pragma unroll
    for (int i = 0; i < 2; ++i) {
      int row = i * 64 + wave * 16 + srow;
      const uint16_t* gp = B + (tn * BN + row) * (long)ldb + k0 + scol;
      __builtin_amdgcn_global_load_lds((gbl_void_t*)(uintptr_t)gp,
          (lds_void_t*)&Bs[i * 2048 + wave * 512], 16, 0, 0);
    }
    __syncthreads();
    bf16x8 a[4], b[4];
#pragma unroll
    for (int f = 0; f < 4; ++f)
      a[f] = *(const bf16x8*)&As[(wm + f * 16 + lrow) * BK + quad * 8];
#pragma unroll
    for (int f = 0; f < 4; ++f)
      b[f] = *(const bf16x8*)&Bs[(wn + f * 16 + lrow) * BK + quad * 8];
#pragma unroll
    for (int fm = 0; fm < 4; ++fm)
#pragma unroll
      for (int fn = 0; fn < 4; ++fn)
        acc[fm][fn] = __builtin_amdgcn_mfma_f32_16x16x32_bf16(
            a[fm], b[fn], acc[fm][fn], 0, 0, 0);
    __syncthreads();
  }
#pragma unroll
  for (int fm = 0; fm < 4; ++fm)
#pragma unroll
    for (int fn = 0; fn < 4; ++fn) {
      long col  = tn * BN + wn + fn * 16 + lrow;
      long row0 = tm * BM + wm + fm * 16 + quad * 4;
#pragma unroll
      for (int r = 0; r < 4; ++r)
        C[(row0 + r) * (long)ldc + col] = acc[fm][fn][r];
    }
}

// ---- fused level kernel, bf16 A (upper levels; round-10 verbatim) ----------
template <bool HAS_F>
__global__ __launch_bounds__(256, 3)
void k_level(const uint16_t* __restrict__ A, int lda, int K,
             const uint16_t* __restrict__ Wg,
             const float* __restrict__ bi, const float* __restrict__ bo,
             const float* __restrict__ bu,
             const float* __restrict__ Fpart,
             uint16_t* __restrict__ Cbf,
             const uint16_t* __restrict__ Xnext,
             uint16_t* __restrict__ xh_next) {
  __shared__ uint16_t As[128 * 64];      // 16 KB
  __shared__ uint16_t Bs[192 * 64];      // 24 KB
  const int tid = threadIdx.x, lane = tid & 63, wave = tid >> 6;
  const int lrow = lane & 15, quad = lane >> 4;
  const int wm = (wave >> 1) * 64, wn = (wave & 1) * 32;

  long tm, tn;
  {
    const int nTm = (int)(gridDim.x >> 3);
    int b = blockIdx.x;
    if ((nTm & 7) == 0) {           // XCD swizzle (dispatch round-robin mod 8)
      int x = b & 7, j = b >> 3, per = nTm >> 3;
      tn = j & 7; tm = (long)x * per + (j >> 3);
    } else { tm = b >> 3; tn = b & 7; }
  }

  f32x4 acc[3][4][2] = {};

  const int srow = lane >> 3;
  const int scol = (((lane & 7) ^ srow) << 3);     // elements
  const int rsw = lrow & 7;
  const int pc[2] = { ((0 + quad) ^ rsw) << 3, ((4 + quad) ^ rsw) << 3 };

  for (int k0 = 0; k0 < K; k0 += 64) {
#pragma unroll
    for (int j = 0; j < 4; ++j) {            // A: rows wave*32 .. +31
      int row = wave * 32 + j * 8 + srow;
      const uint16_t* gp = A + (tm * 128 + row) * (long)lda + k0 + scol;
      __builtin_amdgcn_global_load_lds((gbl_void_t*)(uintptr_t)gp,
          (lds_void_t*)&As[(wave * 32 + j * 8) * 64], 16, 0, 0);
    }
#pragma unroll
    for (int j = 0; j < 6; ++j) {            // B: 24 chunks of 8 rows
      int cc = wave * 6 + j;
      int g  = cc >> 3;
      long grow = (long)g * 512 + tn * 64 + (cc & 7) * 8 + srow;
      const uint16_t* gp = Wg + grow * 1024 + k0 + scol;
      __builtin_amdgcn_global_load_lds((gbl_void_t*)(uintptr_t)gp,
          (lds_void_t*)&Bs[cc * 512], 16, 0, 0);
    }
    __syncthreads();

#pragma unroll
    for (int h = 0; h < 2; ++h) {
      bf16x8 a[4];
#pragma unroll
      for (int f = 0; f < 4; ++f)
        a[f] = *(const bf16x8*)&As[(wm + f * 16 + lrow) * 64 + pc[h]];
#pragma unroll
      for (int g = 0; g < 3; ++g) {
        bf16x8 b0 = *(const bf16x8*)&Bs[(g * 64 + wn + lrow) * 64 + pc[h]];
        bf16x8 b1 = *(const bf16x8*)&Bs[(g * 64 + wn + 16 + lrow) * 64 +
                                        pc[h]];
#pragma unroll
        for (int fm = 0; fm < 4; ++fm) {
          acc[g][fm][0] = __builtin_amdgcn_mfma_f32_16x16x32_bf16(
              a[fm], b0, acc[g][fm][0], 0, 0, 0);
          acc[g][fm][1] = __builtin_amdgcn_mfma_f32_16x16x32_bf16(
              a[fm], b1, acc[g][fm][1], 0, 0, 0);
        }
      }
    }
    __syncthreads();
  }

  // epilogue — C/D layout: col = lane&15, row = quad*4 + r  [HW-verified]
#pragma unroll
  for (int fn = 0; fn < 2; ++fn) {
    long col = tn * 64 + wn + fn * 16 + lrow;
    float biv = bi[col], bov = bo[col], buv = bu[col];
#pragma unroll
    for (int fm = 0; fm < 4; ++fm) {
      long row0 = tm * 128 + wm + fm * 16 + quad * 4;
      long pg   = tm * 8 + (wm >> 4) + fm;
      float hs = 0.f;
#pragma unroll
      for (int r = 0; r < 4; ++r) {
        long row = row0 + r;
        float iv = sig_(acc[0][fm][fn][r] + biv);
        float ov = sig_(acc[1][fm][fn][r] + bov);
        float uv = tanh_(acc[2][fm][fn][r] + buv);
        float c  = iv * uv;
        if (HAS_F) c += Fpart[row * 512 + col];
        Cbf[row * 512 + col] = f2bf(c);
        hs += ov * tanh_(c);
      }
      hs += __shfl_xor(hs, 16, 64);
      hs += __shfl_xor(hs, 32, 64);
      if (quad == 0) {
        xh_next[pg * 1024 + col]       = Xnext[pg * 512 + col];
        xh_next[pg * 1024 + 512 + col] = f2bf(hs);
      }
    }
  }
}

// ---- leaf level kernel, fp32 A with T14 reg-prefetch staging ---------------
// Per K-tile: write A(t) regs->LDS (cvt_pk, swizzled), issue 6 B-DMA, then
// issue A(t+1)'s 8 dwordx4 loads; s_waitcnt vmcnt(8) retires only the B-DMAs
// (A(t+1) stays in flight across compute ~2000cyc). Raw-barrier discipline
// proven correct in r11. K=512 fixed, HAS_F=false.
__global__ __launch_bounds__(256, 3)
void k_level_f32(const float* __restrict__ A,
                 const uint16_t* __restrict__ Wg,
                 const float* __restrict__ bi, const float* __restrict__ bo,
                 const float* __restrict__ bu,
                 uint16_t* __restrict__ Cbf,
                 const uint16_t* __restrict__ Xnext,
                 uint16_t* __restrict__ xh_next) {
  __shared__ uint16_t As[128 * 64];      // 16 KB
  __shared__ uint16_t Bs[192 * 64];      // 24 KB
  const int tid = threadIdx.x, lane = tid & 63, wave = tid >> 6;
  const int lrow = lane & 15, quad = lane >> 4;
  const int wm = (wave >> 1) * 64, wn = (wave & 1) * 32;

  long tm, tn;
  {
    const int nTm = (int)(gridDim.x >> 3);   // 512, multiple of 8
    int b = blockIdx.x;
    int x = b & 7, j = b >> 3, per = nTm >> 3;
    tn = j & 7; tm = (long)x * per + (j >> 3);
  }

  f32x4 acc[3][4][2] = {};

  const int srow = lane >> 3, cch = lane & 7;
  const int scol = ((cch ^ srow) << 3);            // swizzled chunk (elems)
  const int rsw = lrow & 7;
  const int pc[2] = { ((0 + quad) ^ rsw) << 3, ((4 + quad) ^ rsw) << 3 };

  float4 ar0[4], ar1[4];                           // in-flight A tile (32 VGPR)
  auto loadA = [&](int t) {
    int k0 = t * 64;
#pragma unroll
    for (int j = 0; j < 4; ++j) {
      int row = wave * 32 + j * 8 + srow;
      const float* gp = A + (tm * 128 + row) * 512L + k0 + cch * 8;
      ar0[j] = *(const float4*)gp;
      ar1[j] = *(const float4*)(gp + 4);
    }
  };

  loadA(0);
  for (int t = 0; t < 8; ++t) {
    int k0 = t * 64;
    // A(t): cvt + swizzled LDS write (reg dependence waits the loads; by
    // t>=1 they've had a full compute interval to land).
#pragma unroll
    for (int j = 0; j < 4; ++j) {
      int row = wave * 32 + j * 8 + srow;
      u16x8 w;
      w[0] = f2bf(ar0[j].x); w[1] = f2bf(ar0[j].y);
      w[2] = f2bf(ar0[j].z); w[3] = f2bf(ar0[j].w);
      w[4] = f2bf(ar1[j].x); w[5] = f2bf(ar1[j].y);
      w[6] = f2bf(ar1[j].z); w[7] = f2bf(ar1[j].w);
      *(u16x8*)&As[row * 64 + scol] = w;           // phys chunk = cch^row
    }
    // B(t): async DMA (6 per thread)
#pragma unroll
    for (int j = 0; j < 6; ++j) {
      int cc = wave * 6 + j;
      int g  = cc >> 3;
      long grow = (long)g * 512 + tn * 64 + (cc & 7) * 8 + srow;
      const uint16_t* gp = Wg + grow * 1024 + k0 + scol;
      __builtin_amdgcn_global_load_lds((gbl_void_t*)(uintptr_t)gp,
          (lds_void_t*)&Bs[cc * 512], 16, 0, 0);
    }
    __builtin_amdgcn_sched_barrier(0);             // pin DMA-before-loads order
    if (t < 7) {
      loadA(t + 1);                                // 8 loads, stay in flight
      asm volatile("s_waitcnt lgkmcnt(0) vmcnt(8)" ::: "memory");
    } else {
      asm volatile("s_waitcnt lgkmcnt(0) vmcnt(0)" ::: "memory");
    }
    __builtin_amdgcn_s_barrier();

#pragma unroll
    for (int h = 0; h < 2; ++h) {
      bf16x8 a[4];
#pragma unroll
      for (int f = 0; f < 4; ++f)
        a[f] = *(const bf16x8*)&As[(wm + f * 16 + lrow) * 64 + pc[h]];
#pragma unroll
      for (int g = 0; g < 3; ++g) {
        bf16x8 b0 = *(const bf16x8*)&Bs[(g * 64 + wn + lrow) * 64 + pc[h]];
        bf16x8 b1 = *(const bf16x8*)&Bs[(g * 64 + wn + 16 + lrow) * 64 +
                                        pc[h]];
#pragma unroll
        for (int fm = 0; fm < 4; ++fm) {
          acc[g][fm][0] = __builtin_amdgcn_mfma_f32_16x16x32_bf16(
              a[fm], b0, acc[g][fm][0], 0, 0, 0);
          acc[g][fm][1] = __builtin_amdgcn_mfma_f32_16x16x32_bf16(
              a[fm], b1, acc[g][fm][1], 0, 0, 0);
        }
      }
    }
    __builtin_amdgcn_s_barrier();
  }

  // epilogue — C/D layout: col = lane&15, row = quad*4 + r  [HW-verified]
#pragma unroll
  for (int fn = 0; fn < 2; ++fn) {
    long col = tn * 64 + wn + fn * 16 + lrow;
    float biv = bi[col], bov = bo[col], buv = bu[col];
#pragma unroll
    for (int fm = 0; fm < 4; ++fm) {
      long row0 = tm * 128 + wm + fm * 16 + quad * 4;
      long pg   = tm * 8 + (wm >> 4) + fm;
      float hs = 0.f;
#pragma unroll
      for (int r = 0; r < 4; ++r) {
        long row = row0 + r;
        float iv = sig_(acc[0][fm][fn][r] + biv);
        float ov = sig_(acc[1][fm][fn][r] + bov);
        float uv = tanh_(acc[2][fm][fn][r] + buv);
        float c  = iv * uv;
        Cbf[row * 512 + col] = f2bf(c);
        hs += ov * tanh_(c);
      }
      hs += __shfl_xor(hs, 16, 64);
      hs += __shfl_xor(hs, 32, 64);
      if (quad == 0) {
        xh_next[pg * 1024 + col]       = Xnext[pg * 512 + col];
        xh_next[pg * 1024 + 512 + col] = f2bf(hs);
      }
    }
  }
}

// ---- fc GEMM + fused forget-combine (XCD-swizzled, swizzled LDS) -----------
__global__ __launch_bounds__(256, 3)
void k_fc_combine(const uint16_t* __restrict__ Cbf,
                  const uint16_t* __restrict__ Wfc, int ldb,
                  const float* __restrict__ Fx,
                  const float* __restrict__ bfb,
                  float* __restrict__ Fpart) {
  __shared__ uint16_t As[128 * 64];   // 16 KB
  __shared__ uint16_t Bs[128 * 64];   // 16 KB
  const int tid = threadIdx.x, lane = tid & 63, wave = tid >> 6;
  const int lrow = lane & 15, quad = lane >> 4;
  const int wm = (wave >> 1) * 64, wn = (wave & 1) * 64;
  long tm, tn;
  {
    const int nTm = (int)(gridDim.x >> 2);
    int b = blockIdx.x;
    if ((nTm & 7) == 0) {
      int x = b & 7, j = b >> 3, per = nTm >> 3;
      tn = j & 3; tm = (long)x * per + (j >> 2);
    } else { tm = b >> 2; tn = b & 3; }
  }
  const int lda = 512;
  f32x4 acc[4][4] = {};

  const int srow = lane >> 3;
  const int scol = (((lane & 7) ^ srow) << 3);
  const int rsw = lrow & 7;
  const int pc[2] = { ((0 + quad) ^ rsw) << 3, ((4 + quad) ^ rsw) << 3 };

  for (int k0 = 0; k0 < 512; k0 += 64) {
#pragma unroll
    for (int j = 0; j < 4; ++j) {
      int row = wave * 32 + j * 8 + srow;
      const uint16_t* gp = Cbf + (tm * BM + row) * (long)lda + k0 + scol;
      __builtin_amdgcn_global_load_lds((gbl_void_t*)(uintptr_t)gp,
          (lds_void_t*)&As[(wave * 32 + j * 8) * 64], 16, 0, 0);
    }
#pragma unroll
    for (int j = 0; j < 4; ++j) {
      int row = wave * 32 + j * 8 + srow;
      const uint16_t* gp = Wfc + (tn * BN + row) * (long)ldb + k0 + scol;
      __builtin_amdgcn_global_load_lds((gbl_void_t*)(uintptr_t)gp,
          (lds_void_t*)&Bs[(wave * 32 + j * 8) * 64], 16, 0, 0);
    }
    __syncthreads();
#pragma unroll
    for (int h = 0; h < 2; ++h) {
      bf16x8 a[4], b[4];
#pragma unroll
      for (int f = 0; f < 4; ++f)
        a[f] = *(const bf16x8*)&As[(wm + f * 16 + lrow) * 64 + pc[h]];
#pragma unroll
      for (int f = 0; f < 4; ++f)
        b[f] = *(const bf16x8*)&Bs[(wn + f * 16 + lrow) * 64 + pc[h]];
#pragma unroll
      for (int fm = 0; fm < 4; ++fm)
#pragma unroll
        for (int fn = 0; fn < 4; ++fn)
          acc[fm][fn] = __builtin_amdgcn_mfma_f32_16x16x32_bf16(
              a[fm], b[fn], acc[fm][fn], 0, 0, 0);
    }
    __syncthreads();
  }
#pragma unroll
  for (int fm = 0; fm < 4; ++fm) {
    long pg   = tm * 8 + (wm >> 4) + fm;
    long row0 = tm * BM + wm + fm * 16 + quad * 4;
#pragma unroll
    for (int fn = 0; fn < 4; ++fn) {
      long col = tn * BN + wn + fn * 16 + lrow;
      float fx = Fx[pg * 512 + col] + bfb[col];
      float t = 0.f;
#pragma unroll
      for (int r = 0; r < 4; ++r)
        t += sig_(fx + acc[fm][fn][r]) * bf2f(Cbf[(row0 + r) * 512 + col]);
      t += __shfl_xor(t, 16, 64);
      t += __shfl_xor(t, 32, 64);
      if (quad == 0) Fpart[pg * 512 + col] = t;
    }
  }
}

// ---- wave-per-dot kernels (tiny levels) ------------------------------------
__global__ void k_dot_bb(const uint16_t* __restrict__ A, int lda,
                         const uint16_t* __restrict__ B, int ldb,
                         float* __restrict__ C, int ldc,
                         int M, int N, int K) {
  int wid  = (int)((blockIdx.x * (long)blockDim.x + threadIdx.x) >> 6);
  int lane = threadIdx.x & 63;
  if (wid >= M * N) return;
  int m = wid / N, n = wid - m * N;
  const uint16_t* a = A + (long)m * lda;
  const uint16_t* b = B + (long)n * ldb;
  int per = K >> 6, k0 = lane * per;
  float s = 0.f;
  for (int j = 0; j < per; j += 4) {
    ushort4 av = *(const ushort4*)(a + k0 + j);
    ushort4 bv = *(const ushort4*)(b + k0 + j);
    s += bf2f(av.x) * bf2f(bv.x) + bf2f(av.y) * bf2f(bv.y)
       + bf2f(av.z) * bf2f(bv.z) + bf2f(av.w) * bf2f(bv.w);
  }
#pragma unroll
  for (int off = 32; off; off >>= 1) s += __shfl_xor(s, off, 64);
  if (lane == 0) C[(long)m * ldc + n] = s;
}
__global__ void k_dot_f32(const float* __restrict__ A, int lda,
                          const float* __restrict__ B, int ldb,
                          float* __restrict__ C, int ldc,
                          int M, int N, int K) {
  int wid  = (int)((blockIdx.x * (long)blockDim.x + threadIdx.x) >> 6);
  int lane = threadIdx.x & 63;
  if (wid >= M * N) return;
  int m = wid / N, n = wid - m * N;
  const float* a = A + (long)m * lda;
  const float* b = B + (long)n * ldb;
  int per = K >> 6, k0 = lane * per;
  float s = 0.f;
  for (int j = 0; j < per; j += 4) {
    float4 av = *(const float4*)(a + k0 + j);
    float4 bv = *(const float4*)(b + k0 + j);
    s += av.x * bv.x + av.y * bv.y + av.z * bv.z + av.w * bv.w;
  }
#pragma unroll
  for (int off = 32; off; off >>= 1) s += __shfl_xor(s, off, 64);
  if (lane == 0) C[(long)m * ldc + n] = s;
}

// ---- upper-level h_sum + pack xh -------------------------------------------
__global__ void k_hsum_xh4(const float* __restrict__ Hc,
                           const uint16_t* __restrict__ xd,
                           uint16_t* __restrict__ xh, int n) {
  long idx = blockIdx.x * (long)blockDim.x + threadIdx.x;
  if (idx >= (long)n * 128) return;
  long p = idx >> 7; int hq = (int)(idx & 127) << 2;
  const float* hp = Hc + (p << 4) * 512 + hq;
  float4 s = {0.f, 0.f, 0.f, 0.f};
#pragma unroll
  for (int b = 0; b < 16; ++b) {
    float4 v = *(const float4*)(hp + b * 512);
    s.x += v.x; s.y += v.y; s.z += v.z; s.w += v.w;
  }
  *(ushort4*)(xh + p * 1024 + hq) = *(const ushort4*)(xd + p * 512 + hq);
  ushort4 hw = {f2bf(s.x), f2bf(s.y), f2bf(s.z), f2bf(s.w)};
  *(ushort4*)(xh + p * 1024 + 512 + hq) = hw;
}

// ---- final for tiny levels -------------------------------------------------
__global__ void k_final4(const float* __restrict__ G,
                         const float* __restrict__ Fpart,
                         const float* __restrict__ bi,
                         const float* __restrict__ bo,
                         const float* __restrict__ bu,
                         float* __restrict__ H, float* __restrict__ Cv,
                         uint16_t* __restrict__ Cbf, int n) {
  long idx = blockIdx.x * (long)blockDim.x + threadIdx.x;
  if (idx >= (long)n * 128) return;
  long p = idx >> 7; int hq = (int)(idx & 127) << 2;
  const float* g = G + p * 1536;
  float4 gi = *(const float4*)(g + hq);
  float4 go = *(const float4*)(g + 512 + hq);
  float4 gu = *(const float4*)(g + 1024 + hq);
  float4 b_i = *(const float4*)(bi + hq);
  float4 b_o = *(const float4*)(bo + hq);
  float4 b_u = *(const float4*)(bu + hq);
  float4 fp = *(const float4*)(Fpart + p * 512 + hq);
  const float* gip = &gi.x; const float* gop = &go.x; const float* gup = &gu.x;
  const float* bip = &b_i.x; const float* bop = &b_o.x; const float* bup = &b_u.x;
  const float* fpp = &fp.x;
  float4 hv, cv;
  float* hvp = &hv.x; float* cvp = &cv.x;
  ushort4 cw; unsigned short* cwp = &cw.x;
#pragma unroll
  for (int j = 0; j < 4; ++j) {
    float iv = sig_(gip[j] + bip[j]);
    float ov = sig_(gop[j] + bop[j]);
    float uv = tanh_(gup[j] + bup[j]);
    float c  = iv * uv + fpp[j];
    cvp[j] = c;
    cwp[j] = f2bf(c);
    hvp[j] = ov * tanh_(c);
  }
  *(float4*)(H  + p * 512 + hq) = hv;
  *(float4*)(Cv + p * 512 + hq) = cv;
  *(ushort4*)(Cbf + p * 512 + hq) = cw;
}

// ---- fused root tail: combine (16 children) + final, 1 block, 128 thr ------
__global__ void k_root_tail(const float* __restrict__ Fc,
                            const float* __restrict__ Fx,
                            const float* __restrict__ bfb,
                            const float* __restrict__ Cc,
                            const float* __restrict__ G,
                            const float* __restrict__ bi,
                            const float* __restrict__ bo,
                            const float* __restrict__ bu,
                            float* __restrict__ H, float* __restrict__ Cv) {
  int hq = (threadIdx.x & 127) << 2;
  float4 fxv = *(const float4*)(Fx + hq);
  float4 bfv = *(const float4*)(bfb + hq);
  float fx0 = fxv.x + bfv.x, fx1 = fxv.y + bfv.y;
  float fx2 = fxv.z + bfv.z, fx3 = fxv.w + bfv.w;
  float a0 = 0.f, a1 = 0.f, a2 = 0.f, a3 = 0.f;
#pragma unroll 4
  for (int b = 0; b < 16; ++b) {
    float4 f = *(const float4*)(Fc + (long)b * 512 + hq);
    float4 c = *(const float4*)(Cc + (long)b * 512 + hq);
    a0 += sig_(fx0 + f.x) * c.x;
    a1 += sig_(fx1 + f.y) * c.y;
    a2 += sig_(fx2 + f.z) * c.z;
    a3 += sig_(fx3 + f.w) * c.w;
  }
  float fpp[4] = {a0, a1, a2, a3};
  float4 gi = *(const float4*)(G + hq);
  float4 go = *(const float4*)(G + 512 + hq);
  float4 gu = *(const float4*)(G + 1024 + hq);
  float4 b_i = *(const float4*)(bi + hq);
  float4 b_o = *(const float4*)(bo + hq);
  float4 b_u = *(const float4*)(bu + hq);
  const float* gip = &gi.x; const float* gop = &go.x; const float* gup = &gu.x;
  const float* bip = &b_i.x; const float* bop = &b_o.x; const float* bup = &b_u.x;
  float4 hv, cv;
  float* hvp = &hv.x; float* cvp = &cv.x;
#pragma unroll
  for (int j = 0; j < 4; ++j) {
    float iv = sig_(gip[j] + bip[j]);
    float ov = sig_(gop[j] + bop[j]);
    float uv = tanh_(gup[j] + bup[j]);
    float c  = iv * uv + fpp[j];
    cvp[j] = c;
    hvp[j] = ov * tanh_(c);
  }
  *(float4*)(H  + hq) = hv;
  *(float4*)(Cv + hq) = cv;
}

// ---------------------------------------------------------------------------
extern "C" void kernel_launch(void* const* d_in, const int* in_sizes, int n_in,
                              void* d_out, int out_size, void* d_ws, size_t ws_size,
                              hipStream_t stream) {
  const float* x    = (const float*)d_in[0];
  const float* wi_w = (const float*)d_in[1];
  const float* wi_b = (const float*)d_in[2];
  const float* wf_w = (const float*)d_in[3];
  const float* wf_b = (const float*)d_in[4];
  const float* wo_w = (const float*)d_in[5];
  const float* wo_b = (const float*)d_in[6];
  const float* wu_w = (const float*)d_in[7];
  const float* wu_b = (const float*)d_in[8];
  (void)in_sizes; (void)n_in; (void)out_size; (void)ws_size;

  static const long offs[5] = {0, 1, 17, 273, 4369};

  // ---- workspace ----
  char* ws = (char*)d_ws;
  size_t off = 0;
  auto alloc = [&](size_t bytes) -> void* {
    void* p = ws + off;
    off += (bytes + 255) & ~(size_t)255;
    return p;
  };
  uint16_t* Xbf   = (uint16_t*)alloc((size_t)4480 * 512 * 2);  // upper x only
  uint16_t* Wgw   = (uint16_t*)alloc((size_t)2048 * 1024 * 2);
  uint16_t* Wg    = Wgw;
  uint16_t* Wf    = Wgw + (size_t)1536 * 1024;
  float*    FxAll = (float*)alloc((size_t)4480 * 512 * 4);
  uint16_t* Cbf   = (uint16_t*)alloc((size_t)65536 * 512 * 2);
  uint16_t* CbfU  = (uint16_t*)alloc((size_t)4096 * 512 * 2);
  uint16_t* CbfU2 = (uint16_t*)alloc((size_t)256 * 512 * 2);
  uint16_t* xhA   = (uint16_t*)alloc((size_t)4096 * 1024 * 2);
  uint16_t* xhB   = (uint16_t*)alloc((size_t)256 * 1024 * 2);
  uint16_t* xhC   = (uint16_t*)alloc((size_t)16 * 1024 * 2);
  float*    Fpart = (float*)alloc((size_t)4096 * 512 * 4);
  float*    Gf    = (float*)alloc((size_t)16 * 1536 * 4);
  float*    Fc    = (float*)alloc((size_t)16 * 512 * 4);
  float*    HupA  = (float*)alloc((size_t)16 * 512 * 4);
  float*    CupA  = (float*)alloc((size_t)16 * 512 * 4);

  auto blks = [](long n) { return (int)((n + 255) / 256); };

  // ---- converts: upper x only (nodes 0..4368) + weights ----
  {
    long n4 = (long)4369 * 512 / 4;
    k_conv_x<<<2048, 256, 0, stream>>>((const float4*)x, (ushort4*)Xbf, n4);
    k_conv_w<<<2048, 256, 0, stream>>>((const float4*)wi_w, (const float4*)wo_w,
                                       (const float4*)wu_w, (const float4*)wf_w,
                                       (ushort4*)Wgw);
  }

  // ---- Fx for all upper levels (node ids 0..4368, pad to 4480) ----
  {
    dim3 grid(35, 4);
    k_gemm_bt<<<grid, 256, 0, stream>>>(Xbf, 512, Wf, 1024, FxAll, 512, 512);
  }

  // ---- leaf level (M=65536, K=512): A = fp32 x, T14 reg-prefetch cvt ----
  k_level_f32<<<4096, 256, 0, stream>>>(
      x + offs[4] * 512, Wg, wi_b, wo_b, wu_b,
      Cbf, Xbf + offs[3] * 512, xhA);
  k_fc_combine<<<2048, 256, 0, stream>>>(Cbf, Wf + 512, 1024,
                                         FxAll + offs[3] * 512, wf_b, Fpart);

  // ---- level 3 (M=4096, K=1024): nTm=32 ----
  k_level<true><<<256, 256, 0, stream>>>(
      xhA, 1024, 1024, Wg, wi_b, wo_b, wu_b, Fpart,
      CbfU, Xbf + offs[2] * 512, xhB);
  k_fc_combine<<<128, 256, 0, stream>>>(CbfU, Wf + 512, 1024,
                                        FxAll + offs[2] * 512, wf_b, Fpart);

  // ---- level 2 (M=256, K=1024): nTm=2 (plain mapping) ----
  k_level<true><<<16, 256, 0, stream>>>(
      xhB, 1024, 1024, Wg, wi_b, wo_b, wu_b, Fpart,
      CbfU2, Xbf + offs[1] * 512, xhC);
  k_fc_combine<<<8, 256, 0, stream>>>(CbfU2, Wf + 512, 1024,
                                      FxAll + offs[1] * 512, wf_b, Fpart);

  // ---- level 1 (n=16) ----
  {
    long waves = 16L * 1536;
    k_dot_bb<<<(int)((waves * 64 + 255) / 256), 256, 0, stream>>>(
        xhC, 1024, Wg, 1024, Gf, 1536, 16, 1536, 1024);
    k_final4<<<blks(16L * 128), 256, 0, stream>>>(
        Gf, Fpart, wi_b, wo_b, wu_b, HupA, CupA, CbfU2, 16);
  }

  // ---- level 0 (root, exact fp32 fc path) ----
  k_hsum_xh4<<<1, 256, 0, stream>>>(HupA, Xbf + offs[0] * 512, xhC, 1);
  {
    long waves = 1536;
    k_dot_bb<<<(int)((waves * 64 + 255) / 256), 256, 0, stream>>>(
        xhC, 1024, Wg, 1024, Gf, 1536, 1, 1536, 1024);
  }
  {
    long waves = 16L * 512;
    k_dot_f32<<<(int)((waves * 64 + 255) / 256), 256, 0, stream>>>(
        CupA, 512, wf_w + 512, 1024, Fc, 512, 16, 512, 512);
  }
  k_root_tail<<<1, 128, 0, stream>>>(Fc, FxAll, wf_b, CupA, Gf,
                                     wi_b, wo_b, wu_b,
                                     (float*)d_out, (float*)d_out + 512);
}

// Round 6
// 518.351 us; speedup vs baseline: 1.1960x; 1.1960x over previous
//
#include <hip/hip_runtime.h>
#include <stdint.h>
#include <stddef.h>

// ---------------------------------------------------------------------------
// CSTreeLSTM on gfx950. Levels 1,16,256,4096,65536 (x offsets 0,1,17,273,4369).
// Round 14: revert to round-10 core (2-phase k_level/k_fc_combine, T2 XOR
// swizzle both-sides, conflicts=0, 3 blocks/CU, leaf 127us). fp32-A fusion
// abandoned (r12 sync-load +112us; r13 reg-prefetch spilled: WRITE +145MB at
// VGPR cap). Kept from r12/r13: k_root_tail fusion (combine+final, validated)
// and merged k_conv_all (x full + weights in one BW-bound launch).
// ---------------------------------------------------------------------------

typedef __bf16 bf16x8 __attribute__((ext_vector_type(8)));
typedef float  f32x4  __attribute__((ext_vector_type(4)));
typedef void __attribute__((address_space(3))) lds_void_t;
typedef void __attribute__((address_space(1))) gbl_void_t;

__device__ __forceinline__ uint16_t f2bf(float f) {
  union { __bf16 b; uint16_t u; } v;
  v.b = (__bf16)f;              // RTNE, compiler emits v_cvt_pk_bf16_f32
  return v.u;
}
__device__ __forceinline__ float bf2f(uint16_t u) {
  union { uint32_t u; float f; } v; v.u = (uint32_t)u << 16;
  return v.f;
}
// native v_rcp_f32 (~1 ulp) -- error budget is huge
__device__ __forceinline__ float sig_(float x) {
  return __builtin_amdgcn_rcpf(1.0f + __expf(-x));
}
// tanh(x) = 2/(1+exp(-2x)) - 1 : mul+exp+add+rcp+fma, no clamp, inf-safe
__device__ __forceinline__ float tanh_(float x) {
  return __builtin_fmaf(2.f,
      __builtin_amdgcn_rcpf(1.f + __expf(-2.f * x)), -1.f);
}

// ---- merged convert: all x rows + 4 weight matrices ------------------------
__global__ void k_conv_all(const float4* __restrict__ x,
                           ushort4* __restrict__ xdst, long n4x,
                           const float4* __restrict__ w0,
                           const float4* __restrict__ w1,
                           const float4* __restrict__ w2,
                           const float4* __restrict__ w3,
                           ushort4* __restrict__ wdst) {
  const long per4 = (long)512 * 1024 / 4;
  const long total = n4x + 4 * per4;
  long i = blockIdx.x * (long)blockDim.x + threadIdx.x;
  long stride = (long)gridDim.x * blockDim.x;
  for (; i < total; i += stride) {
    float4 v;
    ushort4* d;
    if (i < n4x) {
      v = x[i];
      d = xdst + i;
    } else {
      long j = i - n4x;
      long seg = j / per4, off2 = j - seg * per4;
      const float4* s = (seg == 0) ? w0 : (seg == 1) ? w1
                       : (seg == 2) ? w2 : w3;
      v = s[off2];
      d = wdst + j;
    }
    ushort4 r;
    r.x = f2bf(v.x); r.y = f2bf(v.y); r.z = f2bf(v.z); r.w = f2bf(v.w);
    *d = r;
  }
}

#define BM 128
#define BN 128
#define BK 32

// ---- plain bf16 GEMM (FxAll only, cold path, 140 blocks) -------------------
__global__ __launch_bounds__(256)
void k_gemm_bt(const uint16_t* __restrict__ A, int lda,
               const uint16_t* __restrict__ B, int ldb,
               float* __restrict__ C, int ldc, int K) {
  __shared__ uint16_t As[BM * BK];
  __shared__ uint16_t Bs[BN * BK];
  const int tid = threadIdx.x, lane = tid & 63, wave = tid >> 6;
  const int lrow = lane & 15, quad = lane >> 4;
  const int wm = (wave >> 1) * 64, wn = (wave & 1) * 64;
  const long tm = blockIdx.x, tn = blockIdx.y;
  f32x4 acc[4][4] = {};
  const int srow = lane >> 2, scol = (lane & 3) * 8;
  for (int k0 = 0; k0 < K; k0 += BK) {
#pragma unroll
    for (int i = 0; i < 2; ++i) {
      int row = i * 64 + wave * 16 + srow;
      const uint16_t* gp = A + (tm * BM + row) * (long)lda + k0 + scol;
      __builtin_amdgcn_global_load_lds((gbl_void_t*)(uintptr_t)gp,
          (lds_void_t*)&As[i * 2048 + wave * 512], 16, 0, 0);
    }
#pragma unroll
    for (int i = 0; i < 2; ++i) {
      int row = i * 64 + wave * 16 + srow;
      const uint16_t* gp = B + (tn * BN + row) * (long)ldb + k0 + scol;
      __builtin_amdgcn_global_load_lds((gbl_void_t*)(uintptr_t)gp,
          (lds_void_t*)&Bs[i * 2048 + wave * 512], 16, 0, 0);
    }
    __syncthreads();
    bf16x8 a[4], b[4];
#pragma unroll
    for (int f = 0; f < 4; ++f)
      a[f] = *(const bf16x8*)&As[(wm + f * 16 + lrow) * BK + quad * 8];
#pragma unroll
    for (int f = 0; f < 4; ++f)
      b[f] = *(const bf16x8*)&Bs[(wn + f * 16 + lrow) * BK + quad * 8];
#pragma unroll
    for (int fm = 0; fm < 4; ++fm)
#pragma unroll
      for (int fn = 0; fn < 4; ++fn)
        acc[fm][fn] = __builtin_amdgcn_mfma_f32_16x16x32_bf16(
            a[fm], b[fn], acc[fm][fn], 0, 0, 0);
    __syncthreads();
  }
#pragma unroll
  for (int fm = 0; fm < 4; ++fm)
#pragma unroll
    for (int fn = 0; fn < 4; ++fn) {
      long col  = tn * BN + wn + fn * 16 + lrow;
      long row0 = tm * BM + wm + fm * 16 + quad * 4;
#pragma unroll
      for (int r = 0; r < 4; ++r)
        C[(row0 + r) * (long)ldc + col] = acc[fm][fn][r];
    }
}

// ---- fused level kernel (round-10 verbatim) --------------------------------
// 1-D grid of nTm*8 blocks; XCD swizzle: x=b&7 (XCD), contiguous tm range per
// XCD, tn fastest. 2-phase loop (stage 64-K tile, sync, compute, sync).
// LDS layout: As[row][64], Bs[g*64+row][64] bf16; 16B chunks XOR-swizzled by
// (row&7). Stage pre-swizzles global src col; reads XOR the chunk index.
template <bool HAS_F>
__global__ __launch_bounds__(256, 3)
void k_level(const uint16_t* __restrict__ A, int lda, int K,
             const uint16_t* __restrict__ Wg,
             const float* __restrict__ bi, const float* __restrict__ bo,
             const float* __restrict__ bu,
             const float* __restrict__ Fpart,
             uint16_t* __restrict__ Cbf,
             const uint16_t* __restrict__ Xnext,
             uint16_t* __restrict__ xh_next) {
  __shared__ uint16_t As[128 * 64];      // 16 KB
  __shared__ uint16_t Bs[192 * 64];      // 24 KB
  const int tid = threadIdx.x, lane = tid & 63, wave = tid >> 6;
  const int lrow = lane & 15, quad = lane >> 4;
  const int wm = (wave >> 1) * 64, wn = (wave & 1) * 32;

  long tm, tn;
  {
    const int nTm = (int)(gridDim.x >> 3);
    int b = blockIdx.x;
    if ((nTm & 7) == 0) {           // XCD swizzle (dispatch round-robin mod 8)
      int x = b & 7, j = b >> 3, per = nTm >> 3;
      tn = j & 7; tm = (long)x * per + (j >> 3);
    } else { tm = b >> 3; tn = b & 7; }
  }

  f32x4 acc[3][4][2] = {};

  // stage mapping: 1KB wave-store = 8 rows x 8 chunks of 16B; lane ->
  // (row lane>>3, phys chunk lane&7); fetch logical chunk (lane&7)^(lane>>3)
  // so phys = logical ^ (row&7).  [conflicts measured 0]
  const int srow = lane >> 3;
  const int scol = (((lane & 7) ^ srow) << 3);     // elements
  const int rsw = lrow & 7;
  const int pc[2] = { ((0 + quad) ^ rsw) << 3, ((4 + quad) ^ rsw) << 3 };

  for (int k0 = 0; k0 < K; k0 += 64) {
#pragma unroll
    for (int j = 0; j < 4; ++j) {            // A: rows wave*32 .. +31
      int row = wave * 32 + j * 8 + srow;
      const uint16_t* gp = A + (tm * 128 + row) * (long)lda + k0 + scol;
      __builtin_amdgcn_global_load_lds((gbl_void_t*)(uintptr_t)gp,
          (lds_void_t*)&As[(wave * 32 + j * 8) * 64], 16, 0, 0);
    }
#pragma unroll
    for (int j = 0; j < 6; ++j) {            // B: 24 chunks of 8 rows
      int cc = wave * 6 + j;
      int g  = cc >> 3;
      long grow = (long)g * 512 + tn * 64 + (cc & 7) * 8 + srow;
      const uint16_t* gp = Wg + grow * 1024 + k0 + scol;
      __builtin_amdgcn_global_load_lds((gbl_void_t*)(uintptr_t)gp,
          (lds_void_t*)&Bs[cc * 512], 16, 0, 0);
    }
    __syncthreads();

#pragma unroll
    for (int h = 0; h < 2; ++h) {
      bf16x8 a[4];
#pragma unroll
      for (int f = 0; f < 4; ++f)
        a[f] = *(const bf16x8*)&As[(wm + f * 16 + lrow) * 64 + pc[h]];
#pragma unroll
      for (int g = 0; g < 3; ++g) {
        bf16x8 b0 = *(const bf16x8*)&Bs[(g * 64 + wn + lrow) * 64 + pc[h]];
        bf16x8 b1 = *(const bf16x8*)&Bs[(g * 64 + wn + 16 + lrow) * 64 +
                                        pc[h]];
#pragma unroll
        for (int fm = 0; fm < 4; ++fm) {
          acc[g][fm][0] = __builtin_amdgcn_mfma_f32_16x16x32_bf16(
              a[fm], b0, acc[g][fm][0], 0, 0, 0);
          acc[g][fm][1] = __builtin_amdgcn_mfma_f32_16x16x32_bf16(
              a[fm], b1, acc[g][fm][1], 0, 0, 0);
        }
      }
    }
    __syncthreads();
  }

  // epilogue — C/D layout: col = lane&15, row = quad*4 + r  [HW-verified]
#pragma unroll
  for (int fn = 0; fn < 2; ++fn) {
    long col = tn * 64 + wn + fn * 16 + lrow;
    float biv = bi[col], bov = bo[col], buv = bu[col];
#pragma unroll
    for (int fm = 0; fm < 4; ++fm) {
      long row0 = tm * 128 + wm + fm * 16 + quad * 4;
      long pg   = tm * 8 + (wm >> 4) + fm;
      float hs = 0.f;
#pragma unroll
      for (int r = 0; r < 4; ++r) {
        long row = row0 + r;
        float iv = sig_(acc[0][fm][fn][r] + biv);
        float ov = sig_(acc[1][fm][fn][r] + bov);
        float uv = tanh_(acc[2][fm][fn][r] + buv);
        float c  = iv * uv;
        if (HAS_F) c += Fpart[row * 512 + col];
        Cbf[row * 512 + col] = f2bf(c);
        hs += ov * tanh_(c);
      }
      hs += __shfl_xor(hs, 16, 64);
      hs += __shfl_xor(hs, 32, 64);
      if (quad == 0) {
        xh_next[pg * 1024 + col]       = Xnext[pg * 512 + col];
        xh_next[pg * 1024 + 512 + col] = f2bf(hs);
      }
    }
  }
}

// ---- fc GEMM + fused forget-combine (round-10 verbatim) --------------------
__global__ __launch_bounds__(256, 3)
void k_fc_combine(const uint16_t* __restrict__ Cbf,
                  const uint16_t* __restrict__ Wfc, int ldb,
                  const float* __restrict__ Fx,
                  const float* __restrict__ bfb,
                  float* __restrict__ Fpart) {
  __shared__ uint16_t As[128 * 64];   // 16 KB
  __shared__ uint16_t Bs[128 * 64];   // 16 KB
  const int tid = threadIdx.x, lane = tid & 63, wave = tid >> 6;
  const int lrow = lane & 15, quad = lane >> 4;
  const int wm = (wave >> 1) * 64, wn = (wave & 1) * 64;
  long tm, tn;
  {
    const int nTm = (int)(gridDim.x >> 2);
    int b = blockIdx.x;
    if ((nTm & 7) == 0) {
      int x = b & 7, j = b >> 3, per = nTm >> 3;
      tn = j & 3; tm = (long)x * per + (j >> 2);
    } else { tm = b >> 2; tn = b & 3; }
  }
  const int lda = 512;
  f32x4 acc[4][4] = {};

  const int srow = lane >> 3;
  const int scol = (((lane & 7) ^ srow) << 3);
  const int rsw = lrow & 7;
  const int pc[2] = { ((0 + quad) ^ rsw) << 3, ((4 + quad) ^ rsw) << 3 };

  for (int k0 = 0; k0 < 512; k0 += 64) {
#pragma unroll
    for (int j = 0; j < 4; ++j) {
      int row = wave * 32 + j * 8 + srow;
      const uint16_t* gp = Cbf + (tm * BM + row) * (long)lda + k0 + scol;
      __builtin_amdgcn_global_load_lds((gbl_void_t*)(uintptr_t)gp,
          (lds_void_t*)&As[(wave * 32 + j * 8) * 64], 16, 0, 0);
    }
#pragma unroll
    for (int j = 0; j < 4; ++j) {
      int row = wave * 32 + j * 8 + srow;
      const uint16_t* gp = Wfc + (tn * BN + row) * (long)ldb + k0 + scol;
      __builtin_amdgcn_global_load_lds((gbl_void_t*)(uintptr_t)gp,
          (lds_void_t*)&Bs[(wave * 32 + j * 8) * 64], 16, 0, 0);
    }
    __syncthreads();
#pragma unroll
    for (int h = 0; h < 2; ++h) {
      bf16x8 a[4], b[4];
#pragma unroll
      for (int f = 0; f < 4; ++f)
        a[f] = *(const bf16x8*)&As[(wm + f * 16 + lrow) * 64 + pc[h]];
#pragma unroll
      for (int f = 0; f < 4; ++f)
        b[f] = *(const bf16x8*)&Bs[(wn + f * 16 + lrow) * 64 + pc[h]];
#pragma unroll
      for (int fm = 0; fm < 4; ++fm)
#pragma unroll
        for (int fn = 0; fn < 4; ++fn)
          acc[fm][fn] = __builtin_amdgcn_mfma_f32_16x16x32_bf16(
              a[fm], b[fn], acc[fm][fn], 0, 0, 0);
    }
    __syncthreads();
  }
#pragma unroll
  for (int fm = 0; fm < 4; ++fm) {
    long pg   = tm * 8 + (wm >> 4) + fm;
    long row0 = tm * BM + wm + fm * 16 + quad * 4;
#pragma unroll
    for (int fn = 0; fn < 4; ++fn) {
      long col = tn * BN + wn + fn * 16 + lrow;
      float fx = Fx[pg * 512 + col] + bfb[col];
      float t = 0.f;
#pragma unroll
      for (int r = 0; r < 4; ++r)
        t += sig_(fx + acc[fm][fn][r]) * bf2f(Cbf[(row0 + r) * 512 + col]);
      t += __shfl_xor(t, 16, 64);
      t += __shfl_xor(t, 32, 64);
      if (quad == 0) Fpart[pg * 512 + col] = t;
    }
  }
}

// ---- wave-per-dot kernels (tiny levels) ------------------------------------
__global__ void k_dot_bb(const uint16_t* __restrict__ A, int lda,
                         const uint16_t* __restrict__ B, int ldb,
                         float* __restrict__ C, int ldc,
                         int M, int N, int K) {
  int wid  = (int)((blockIdx.x * (long)blockDim.x + threadIdx.x) >> 6);
  int lane = threadIdx.x & 63;
  if (wid >= M * N) return;
  int m = wid / N, n = wid - m * N;
  const uint16_t* a = A + (long)m * lda;
  const uint16_t* b = B + (long)n * ldb;
  int per = K >> 6, k0 = lane * per;
  float s = 0.f;
  for (int j = 0; j < per; j += 4) {
    ushort4 av = *(const ushort4*)(a + k0 + j);
    ushort4 bv = *(const ushort4*)(b + k0 + j);
    s += bf2f(av.x) * bf2f(bv.x) + bf2f(av.y) * bf2f(bv.y)
       + bf2f(av.z) * bf2f(bv.z) + bf2f(av.w) * bf2f(bv.w);
  }
#pragma unroll
  for (int off = 32; off; off >>= 1) s += __shfl_xor(s, off, 64);
  if (lane == 0) C[(long)m * ldc + n] = s;
}
__global__ void k_dot_f32(const float* __restrict__ A, int lda,
                          const float* __restrict__ B, int ldb,
                          float* __restrict__ C, int ldc,
                          int M, int N, int K) {
  int wid  = (int)((blockIdx.x * (long)blockDim.x + threadIdx.x) >> 6);
  int lane = threadIdx.x & 63;
  if (wid >= M * N) return;
  int m = wid / N, n = wid - m * N;
  const float* a = A + (long)m * lda;
  const float* b = B + (long)n * ldb;
  int per = K >> 6, k0 = lane * per;
  float s = 0.f;
  for (int j = 0; j < per; j += 4) {
    float4 av = *(const float4*)(a + k0 + j);
    float4 bv = *(const float4*)(b + k0 + j);
    s += av.x * bv.x + av.y * bv.y + av.z * bv.z + av.w * bv.w;
  }
#pragma unroll
  for (int off = 32; off; off >>= 1) s += __shfl_xor(s, off, 64);
  if (lane == 0) C[(long)m * ldc + n] = s;
}

// ---- upper-level h_sum + pack xh -------------------------------------------
__global__ void k_hsum_xh4(const float* __restrict__ Hc,
                           const uint16_t* __restrict__ xd,
                           uint16_t* __restrict__ xh, int n) {
  long idx = blockIdx.x * (long)blockDim.x + threadIdx.x;
  if (idx >= (long)n * 128) return;
  long p = idx >> 7; int hq = (int)(idx & 127) << 2;
  const float* hp = Hc + (p << 4) * 512 + hq;
  float4 s = {0.f, 0.f, 0.f, 0.f};
#pragma unroll
  for (int b = 0; b < 16; ++b) {
    float4 v = *(const float4*)(hp + b * 512);
    s.x += v.x; s.y += v.y; s.z += v.z; s.w += v.w;
  }
  *(ushort4*)(xh + p * 1024 + hq) = *(const ushort4*)(xd + p * 512 + hq);
  ushort4 hw = {f2bf(s.x), f2bf(s.y), f2bf(s.z), f2bf(s.w)};
  *(ushort4*)(xh + p * 1024 + 512 + hq) = hw;
}

// ---- final for tiny levels -------------------------------------------------
__global__ void k_final4(const float* __restrict__ G,
                         const float* __restrict__ Fpart,
                         const float* __restrict__ bi,
                         const float* __restrict__ bo,
                         const float* __restrict__ bu,
                         float* __restrict__ H, float* __restrict__ Cv,
                         uint16_t* __restrict__ Cbf, int n) {
  long idx = blockIdx.x * (long)blockDim.x + threadIdx.x;
  if (idx >= (long)n * 128) return;
  long p = idx >> 7; int hq = (int)(idx & 127) << 2;
  const float* g = G + p * 1536;
  float4 gi = *(const float4*)(g + hq);
  float4 go = *(const float4*)(g + 512 + hq);
  float4 gu = *(const float4*)(g + 1024 + hq);
  float4 b_i = *(const float4*)(bi + hq);
  float4 b_o = *(const float4*)(bo + hq);
  float4 b_u = *(const float4*)(bu + hq);
  float4 fp = *(const float4*)(Fpart + p * 512 + hq);
  const float* gip = &gi.x; const float* gop = &go.x; const float* gup = &gu.x;
  const float* bip = &b_i.x; const float* bop = &b_o.x; const float* bup = &b_u.x;
  const float* fpp = &fp.x;
  float4 hv, cv;
  float* hvp = &hv.x; float* cvp = &cv.x;
  ushort4 cw; unsigned short* cwp = &cw.x;
#pragma unroll
  for (int j = 0; j < 4; ++j) {
    float iv = sig_(gip[j] + bip[j]);
    float ov = sig_(gop[j] + bop[j]);
    float uv = tanh_(gup[j] + bup[j]);
    float c  = iv * uv + fpp[j];
    cvp[j] = c;
    cwp[j] = f2bf(c);
    hvp[j] = ov * tanh_(c);
  }
  *(float4*)(H  + p * 512 + hq) = hv;
  *(float4*)(Cv + p * 512 + hq) = cv;
  *(ushort4*)(Cbf + p * 512 + hq) = cw;
}

// ---- fused root tail: combine (16 children) + final, 1 block, 128 thr ------
__global__ void k_root_tail(const float* __restrict__ Fc,
                            const float* __restrict__ Fx,
                            const float* __restrict__ bfb,
                            const float* __restrict__ Cc,
                            const float* __restrict__ G,
                            const float* __restrict__ bi,
                            const float* __restrict__ bo,
                            const float* __restrict__ bu,
                            float* __restrict__ H, float* __restrict__ Cv) {
  int hq = (threadIdx.x & 127) << 2;
  float4 fxv = *(const float4*)(Fx + hq);
  float4 bfv = *(const float4*)(bfb + hq);
  float fx0 = fxv.x + bfv.x, fx1 = fxv.y + bfv.y;
  float fx2 = fxv.z + bfv.z, fx3 = fxv.w + bfv.w;
  float a0 = 0.f, a1 = 0.f, a2 = 0.f, a3 = 0.f;
#pragma unroll 4
  for (int b = 0; b < 16; ++b) {
    float4 f = *(const float4*)(Fc + (long)b * 512 + hq);
    float4 c = *(const float4*)(Cc + (long)b * 512 + hq);
    a0 += sig_(fx0 + f.x) * c.x;
    a1 += sig_(fx1 + f.y) * c.y;
    a2 += sig_(fx2 + f.z) * c.z;
    a3 += sig_(fx3 + f.w) * c.w;
  }
  float fpp[4] = {a0, a1, a2, a3};
  float4 gi = *(const float4*)(G + hq);
  float4 go = *(const float4*)(G + 512 + hq);
  float4 gu = *(const float4*)(G + 1024 + hq);
  float4 b_i = *(const float4*)(bi + hq);
  float4 b_o = *(const float4*)(bo + hq);
  float4 b_u = *(const float4*)(bu + hq);
  const float* gip = &gi.x; const float* gop = &go.x; const float* gup = &gu.x;
  const float* bip = &b_i.x; const float* bop = &b_o.x; const float* bup = &b_u.x;
  float4 hv, cv;
  float* hvp = &hv.x; float* cvp = &cv.x;
#pragma unroll
  for (int j = 0; j < 4; ++j) {
    float iv = sig_(gip[j] + bip[j]);
    float ov = sig_(gop[j] + bop[j]);
    float uv = tanh_(gup[j] + bup[j]);
    float c  = iv * uv + fpp[j];
    cvp[j] = c;
    hvp[j] = ov * tanh_(c);
  }
  *(float4*)(H  + hq) = hv;
  *(float4*)(Cv + hq) = cv;
}

// ---------------------------------------------------------------------------
extern "C" void kernel_launch(void* const* d_in, const int* in_sizes, int n_in,
                              void* d_out, int out_size, void* d_ws, size_t ws_size,
                              hipStream_t stream) {
  const float* x    = (const float*)d_in[0];
  const float* wi_w = (const float*)d_in[1];
  const float* wi_b = (const float*)d_in[2];
  const float* wf_w = (const float*)d_in[3];
  const float* wf_b = (const float*)d_in[4];
  const float* wo_w = (const float*)d_in[5];
  const float* wo_b = (const float*)d_in[6];
  const float* wu_w = (const float*)d_in[7];
  const float* wu_b = (const float*)d_in[8];
  (void)in_sizes; (void)n_in; (void)out_size; (void)ws_size;

  static const long offs[5] = {0, 1, 17, 273, 4369};
  const long NTOT = 69905;

  // ---- workspace ----
  char* ws = (char*)d_ws;
  size_t off = 0;
  auto alloc = [&](size_t bytes) -> void* {
    void* p = ws + off;
    off += (bytes + 255) & ~(size_t)255;
    return p;
  };
  uint16_t* Xbf   = (uint16_t*)alloc(NTOT * 512 * 2);
  uint16_t* Wgw   = (uint16_t*)alloc((size_t)2048 * 1024 * 2);
  uint16_t* Wg    = Wgw;
  uint16_t* Wf    = Wgw + (size_t)1536 * 1024;
  float*    FxAll = (float*)alloc((size_t)4480 * 512 * 4);
  uint16_t* Cbf   = (uint16_t*)alloc((size_t)65536 * 512 * 2);
  uint16_t* CbfU  = (uint16_t*)alloc((size_t)4096 * 512 * 2);
  uint16_t* CbfU2 = (uint16_t*)alloc((size_t)256 * 512 * 2);
  uint16_t* xhA   = (uint16_t*)alloc((size_t)4096 * 1024 * 2);
  uint16_t* xhB   = (uint16_t*)alloc((size_t)256 * 1024 * 2);
  uint16_t* xhC   = (uint16_t*)alloc((size_t)16 * 1024 * 2);
  float*    Fpart = (float*)alloc((size_t)4096 * 512 * 4);
  float*    Gf    = (float*)alloc((size_t)16 * 1536 * 4);
  float*    Fc    = (float*)alloc((size_t)16 * 512 * 4);
  float*    HupA  = (float*)alloc((size_t)16 * 512 * 4);
  float*    CupA  = (float*)alloc((size_t)16 * 512 * 4);

  auto blks = [](long n) { return (int)((n + 255) / 256); };

  // ---- merged convert: all x + 4 weight matrices ----
  {
    long n4x = NTOT * 512 / 4;
    k_conv_all<<<8192, 256, 0, stream>>>(
        (const float4*)x, (ushort4*)Xbf, n4x,
        (const float4*)wi_w, (const float4*)wo_w,
        (const float4*)wu_w, (const float4*)wf_w, (ushort4*)Wgw);
  }

  // ---- Fx for all upper levels (node ids 0..4368, pad to 4480) ----
  {
    dim3 grid(35, 4);
    k_gemm_bt<<<grid, 256, 0, stream>>>(Xbf, 512, Wf, 1024, FxAll, 512, 512);
  }

  // ---- leaf level (M=65536, K=512): nTm=512, 1-D swizzled grid ----
  k_level<false><<<4096, 256, 0, stream>>>(
      Xbf + offs[4] * 512, 512, 512, Wg, wi_b, wo_b, wu_b, nullptr,
      Cbf, Xbf + offs[3] * 512, xhA);
  k_fc_combine<<<2048, 256, 0, stream>>>(Cbf, Wf + 512, 1024,
                                         FxAll + offs[3] * 512, wf_b, Fpart);

  // ---- level 3 (M=4096, K=1024): nTm=32 ----
  k_level<true><<<256, 256, 0, stream>>>(
      xhA, 1024, 1024, Wg, wi_b, wo_b, wu_b, Fpart,
      CbfU, Xbf + offs[2] * 512, xhB);
  k_fc_combine<<<128, 256, 0, stream>>>(CbfU, Wf + 512, 1024,
                                        FxAll + offs[2] * 512, wf_b, Fpart);

  // ---- level 2 (M=256, K=1024): nTm=2 (plain mapping) ----
  k_level<true><<<16, 256, 0, stream>>>(
      xhB, 1024, 1024, Wg, wi_b, wo_b, wu_b, Fpart,
      CbfU2, Xbf + offs[1] * 512, xhC);
  k_fc_combine<<<8, 256, 0, stream>>>(CbfU2, Wf + 512, 1024,
                                      FxAll + offs[1] * 512, wf_b, Fpart);

  // ---- level 1 (n=16) ----
  {
    long waves = 16L * 1536;
    k_dot_bb<<<(int)((waves * 64 + 255) / 256), 256, 0, stream>>>(
        xhC, 1024, Wg, 1024, Gf, 1536, 16, 1536, 1024);
    k_final4<<<blks(16L * 128), 256, 0, stream>>>(
        Gf, Fpart, wi_b, wo_b, wu_b, HupA, CupA, CbfU2, 16);
  }

  // ---- level 0 (root, exact fp32 fc path) ----
  k_hsum_xh4<<<1, 256, 0, stream>>>(HupA, Xbf + offs[0] * 512, xhC, 1);
  {
    long waves = 1536;
    k_dot_bb<<<(int)((waves * 64 + 255) / 256), 256, 0, stream>>>(
        xhC, 1024, Wg, 1024, Gf, 1536, 1, 1536, 1024);
  }
  {
    long waves = 16L * 512;
    k_dot_f32<<<(int)((waves * 64 + 255) / 256), 256, 0, stream>>>(
        CupA, 512, wf_w + 512, 1024, Fc, 512, 16, 512, 512);
  }
  k_root_tail<<<1, 128, 0, stream>>>(Fc, FxAll, wf_b, CupA, Gf,
                                     wi_b, wo_b, wu_b,
                                     (float*)d_out, (float*)d_out + 512);
}

// Round 7
// 494.855 us; speedup vs baseline: 1.2528x; 1.0475x over previous
//
#include <hip/hip_runtime.h>
#include <stdint.h>
#include <stddef.h>

// ---------------------------------------------------------------------------
// CSTreeLSTM on gfx950. Levels 1,16,256,4096,65536 (x offsets 0,1,17,273,4369).
// Round 15: round-14 core retained (2-phase + T2 swizzle, leaf 127us,
// conflicts=0). New: MF-templated k_level/k_fc_combine — MF=2 (BM=64) for
// levels 3/2 doubles block count (1->2 blocks/CU) on the latency-bound mid
// levels; leaf stays MF=4 (identical codegen). Tail fusions: k_lvl1_tail
// (final4+hsum in one block, H in LDS) and k_dot_merge (root dot_bb + dot_f32
// wave-split). 14 -> 12 launches.
// ---------------------------------------------------------------------------

typedef __bf16 bf16x8 __attribute__((ext_vector_type(8)));
typedef float  f32x4  __attribute__((ext_vector_type(4)));
typedef void __attribute__((address_space(3))) lds_void_t;
typedef void __attribute__((address_space(1))) gbl_void_t;

__device__ __forceinline__ uint16_t f2bf(float f) {
  union { __bf16 b; uint16_t u; } v;
  v.b = (__bf16)f;              // RTNE, compiler emits v_cvt_pk_bf16_f32
  return v.u;
}
__device__ __forceinline__ float bf2f(uint16_t u) {
  union { uint32_t u; float f; } v; v.u = (uint32_t)u << 16;
  return v.f;
}
// native v_rcp_f32 (~1 ulp) -- error budget is huge
__device__ __forceinline__ float sig_(float x) {
  return __builtin_amdgcn_rcpf(1.0f + __expf(-x));
}
// tanh(x) = 2/(1+exp(-2x)) - 1 : mul+exp+add+rcp+fma, no clamp, inf-safe
__device__ __forceinline__ float tanh_(float x) {
  return __builtin_fmaf(2.f,
      __builtin_amdgcn_rcpf(1.f + __expf(-2.f * x)), -1.f);
}

// ---- merged convert: all x rows + 4 weight matrices ------------------------
__global__ void k_conv_all(const float4* __restrict__ x,
                           ushort4* __restrict__ xdst, long n4x,
                           const float4* __restrict__ w0,
                           const float4* __restrict__ w1,
                           const float4* __restrict__ w2,
                           const float4* __restrict__ w3,
                           ushort4* __restrict__ wdst) {
  const long per4 = (long)512 * 1024 / 4;
  const long total = n4x + 4 * per4;
  long i = blockIdx.x * (long)blockDim.x + threadIdx.x;
  long stride = (long)gridDim.x * blockDim.x;
  for (; i < total; i += stride) {
    float4 v;
    ushort4* d;
    if (i < n4x) {
      v = x[i];
      d = xdst + i;
    } else {
      long j = i - n4x;
      long seg = j / per4, off2 = j - seg * per4;
      const float4* s = (seg == 0) ? w0 : (seg == 1) ? w1
                       : (seg == 2) ? w2 : w3;
      v = s[off2];
      d = wdst + j;
    }
    ushort4 r;
    r.x = f2bf(v.x); r.y = f2bf(v.y); r.z = f2bf(v.z); r.w = f2bf(v.w);
    *d = r;
  }
}

#define BM 128
#define BN 128
#define BK 32

// ---- plain bf16 GEMM (FxAll only, cold path, 140 blocks) -------------------
__global__ __launch_bounds__(256)
void k_gemm_bt(const uint16_t* __restrict__ A, int lda,
               const uint16_t* __restrict__ B, int ldb,
               float* __restrict__ C, int ldc, int K) {
  __shared__ uint16_t As[BM * BK];
  __shared__ uint16_t Bs[BN * BK];
  const int tid = threadIdx.x, lane = tid & 63, wave = tid >> 6;
  const int lrow = lane & 15, quad = lane >> 4;
  const int wm = (wave >> 1) * 64, wn = (wave & 1) * 64;
  const long tm = blockIdx.x, tn = blockIdx.y;
  f32x4 acc[4][4] = {};
  const int srow = lane >> 2, scol = (lane & 3) * 8;
  for (int k0 = 0; k0 < K; k0 += BK) {
#pragma unroll
    for (int i = 0; i < 2; ++i) {
      int row = i * 64 + wave * 16 + srow;
      const uint16_t* gp = A + (tm * BM + row) * (long)lda + k0 + scol;
      __builtin_amdgcn_global_load_lds((gbl_void_t*)(uintptr_t)gp,
          (lds_void_t*)&As[i * 2048 + wave * 512], 16, 0, 0);
    }
#pragma unroll
    for (int i = 0; i < 2; ++i) {
      int row = i * 64 + wave * 16 + srow;
      const uint16_t* gp = B + (tn * BN + row) * (long)ldb + k0 + scol;
      __builtin_amdgcn_global_load_lds((gbl_void_t*)(uintptr_t)gp,
          (lds_void_t*)&Bs[i * 2048 + wave * 512], 16, 0, 0);
    }
    __syncthreads();
    bf16x8 a[4], b[4];
#pragma unroll
    for (int f = 0; f < 4; ++f)
      a[f] = *(const bf16x8*)&As[(wm + f * 16 + lrow) * BK + quad * 8];
#pragma unroll
    for (int f = 0; f < 4; ++f)
      b[f] = *(const bf16x8*)&Bs[(wn + f * 16 + lrow) * BK + quad * 8];
#pragma unroll
    for (int fm = 0; fm < 4; ++fm)
#pragma unroll
      for (int fn = 0; fn < 4; ++fn)
        acc[fm][fn] = __builtin_amdgcn_mfma_f32_16x16x32_bf16(
            a[fm], b[fn], acc[fm][fn], 0, 0, 0);
    __syncthreads();
  }
#pragma unroll
  for (int fm = 0; fm < 4; ++fm)
#pragma unroll
    for (int fn = 0; fn < 4; ++fn) {
      long col  = tn * BN + wn + fn * 16 + lrow;
      long row0 = tm * BM + wm + fm * 16 + quad * 4;
#pragma unroll
      for (int r = 0; r < 4; ++r)
        C[(row0 + r) * (long)ldc + col] = acc[fm][fn][r];
    }
}

// ---- fused level kernel (MF-templated: BM = MF*32) -------------------------
// 1-D grid of nTm*8 blocks; XCD swizzle when nTm%8==0. 2-phase loop.
// LDS: As[row][64], Bs[g*64+row][64] bf16; 16B chunks XOR-swizzled by (row&7),
// stage pre-swizzles global src col; reads XOR the chunk index. [conflicts=0]
template <bool HAS_F, int MF>
__global__ __launch_bounds__(256, 3)
void k_level(const uint16_t* __restrict__ A, int lda, int K,
             const uint16_t* __restrict__ Wg,
             const float* __restrict__ bi, const float* __restrict__ bo,
             const float* __restrict__ bu,
             const float* __restrict__ Fpart,
             uint16_t* __restrict__ Cbf,
             const uint16_t* __restrict__ Xnext,
             uint16_t* __restrict__ xh_next) {
  constexpr int BMT = MF * 32;
  __shared__ uint16_t As[BMT * 64];      // MF=4: 16 KB, MF=2: 8 KB
  __shared__ uint16_t Bs[192 * 64];      // 24 KB
  const int tid = threadIdx.x, lane = tid & 63, wave = tid >> 6;
  const int lrow = lane & 15, quad = lane >> 4;
  const int wm = (wave >> 1) * (MF * 16), wn = (wave & 1) * 32;

  long tm, tn;
  {
    const int nTm = (int)(gridDim.x >> 3);
    int b = blockIdx.x;
    if ((nTm & 7) == 0) {           // XCD swizzle (dispatch round-robin mod 8)
      int x = b & 7, j = b >> 3, per = nTm >> 3;
      tn = j & 7; tm = (long)x * per + (j >> 3);
    } else { tm = b >> 3; tn = b & 7; }
  }

  f32x4 acc[3][MF][2] = {};

  const int srow = lane >> 3;
  const int scol = (((lane & 7) ^ srow) << 3);     // elements
  const int rsw = lrow & 7;
  const int pc[2] = { ((0 + quad) ^ rsw) << 3, ((4 + quad) ^ rsw) << 3 };

  for (int k0 = 0; k0 < K; k0 += 64) {
#pragma unroll
    for (int j = 0; j < MF; ++j) {           // A: BMT rows, wave*MF+j groups
      int grp = wave * MF + j;
      int row = grp * 8 + srow;
      const uint16_t* gp = A + (tm * BMT + row) * (long)lda + k0 + scol;
      __builtin_amdgcn_global_load_lds((gbl_void_t*)(uintptr_t)gp,
          (lds_void_t*)&As[grp * 512], 16, 0, 0);
    }
#pragma unroll
    for (int j = 0; j < 6; ++j) {            // B: 24 chunks of 8 rows
      int cc = wave * 6 + j;
      int g  = cc >> 3;
      long grow = (long)g * 512 + tn * 64 + (cc & 7) * 8 + srow;
      const uint16_t* gp = Wg + grow * 1024 + k0 + scol;
      __builtin_amdgcn_global_load_lds((gbl_void_t*)(uintptr_t)gp,
          (lds_void_t*)&Bs[cc * 512], 16, 0, 0);
    }
    __syncthreads();

#pragma unroll
    for (int h = 0; h < 2; ++h) {
      bf16x8 a[MF];
#pragma unroll
      for (int f = 0; f < MF; ++f)
        a[f] = *(const bf16x8*)&As[(wm + f * 16 + lrow) * 64 + pc[h]];
#pragma unroll
      for (int g = 0; g < 3; ++g) {
        bf16x8 b0 = *(const bf16x8*)&Bs[(g * 64 + wn + lrow) * 64 + pc[h]];
        bf16x8 b1 = *(const bf16x8*)&Bs[(g * 64 + wn + 16 + lrow) * 64 +
                                        pc[h]];
#pragma unroll
        for (int fm = 0; fm < MF; ++fm) {
          acc[g][fm][0] = __builtin_amdgcn_mfma_f32_16x16x32_bf16(
              a[fm], b0, acc[g][fm][0], 0, 0, 0);
          acc[g][fm][1] = __builtin_amdgcn_mfma_f32_16x16x32_bf16(
              a[fm], b1, acc[g][fm][1], 0, 0, 0);
        }
      }
    }
    __syncthreads();
  }

  // epilogue — C/D layout: col = lane&15, row = quad*4 + r  [HW-verified]
#pragma unroll
  for (int fn = 0; fn < 2; ++fn) {
    long col = tn * 64 + wn + fn * 16 + lrow;
    float biv = bi[col], bov = bo[col], buv = bu[col];
#pragma unroll
    for (int fm = 0; fm < MF; ++fm) {
      long row0 = tm * BMT + wm + fm * 16 + quad * 4;
      long pg   = tm * (BMT / 16) + (wm >> 4) + fm;
      float hs = 0.f;
#pragma unroll
      for (int r = 0; r < 4; ++r) {
        long row = row0 + r;
        float iv = sig_(acc[0][fm][fn][r] + biv);
        float ov = sig_(acc[1][fm][fn][r] + bov);
        float uv = tanh_(acc[2][fm][fn][r] + buv);
        float c  = iv * uv;
        if (HAS_F) c += Fpart[row * 512 + col];
        Cbf[row * 512 + col] = f2bf(c);
        hs += ov * tanh_(c);
      }
      hs += __shfl_xor(hs, 16, 64);
      hs += __shfl_xor(hs, 32, 64);
      if (quad == 0) {
        xh_next[pg * 1024 + col]       = Xnext[pg * 512 + col];
        xh_next[pg * 1024 + 512 + col] = f2bf(hs);
      }
    }
  }
}

// ---- fc GEMM + fused forget-combine (MF-templated) -------------------------
template <int MF>
__global__ __launch_bounds__(256, 3)
void k_fc_combine(const uint16_t* __restrict__ Cbf,
                  const uint16_t* __restrict__ Wfc, int ldb,
                  const float* __restrict__ Fx,
                  const float* __restrict__ bfb,
                  float* __restrict__ Fpart) {
  constexpr int BMT = MF * 32;
  __shared__ uint16_t As[BMT * 64];   // MF=4: 16 KB, MF=2: 8 KB
  __shared__ uint16_t Bs[128 * 64];   // 16 KB
  const int tid = threadIdx.x, lane = tid & 63, wave = tid >> 6;
  const int lrow = lane & 15, quad = lane >> 4;
  const int wm = (wave >> 1) * (MF * 16), wn = (wave & 1) * 64;
  long tm, tn;
  {
    const int nTm = (int)(gridDim.x >> 2);
    int b = blockIdx.x;
    if ((nTm & 7) == 0) {
      int x = b & 7, j = b >> 3, per = nTm >> 3;
      tn = j & 3; tm = (long)x * per + (j >> 2);
    } else { tm = b >> 2; tn = b & 3; }
  }
  const int lda = 512;
  f32x4 acc[MF][4] = {};

  const int srow = lane >> 3;
  const int scol = (((lane & 7) ^ srow) << 3);
  const int rsw = lrow & 7;
  const int pc[2] = { ((0 + quad) ^ rsw) << 3, ((4 + quad) ^ rsw) << 3 };

  for (int k0 = 0; k0 < 512; k0 += 64) {
#pragma unroll
    for (int j = 0; j < MF; ++j) {
      int grp = wave * MF + j;
      int row = grp * 8 + srow;
      const uint16_t* gp = Cbf + (tm * BMT + row) * (long)lda + k0 + scol;
      __builtin_amdgcn_global_load_lds((gbl_void_t*)(uintptr_t)gp,
          (lds_void_t*)&As[grp * 512], 16, 0, 0);
    }
#pragma unroll
    for (int j = 0; j < 4; ++j) {
      int row = wave * 32 + j * 8 + srow;
      const uint16_t* gp = Wfc + (tn * BN + row) * (long)ldb + k0 + scol;
      __builtin_amdgcn_global_load_lds((gbl_void_t*)(uintptr_t)gp,
          (lds_void_t*)&Bs[(wave * 32 + j * 8) * 64], 16, 0, 0);
    }
    __syncthreads();
#pragma unroll
    for (int h = 0; h < 2; ++h) {
      bf16x8 a[MF], b[4];
#pragma unroll
      for (int f = 0; f < MF; ++f)
        a[f] = *(const bf16x8*)&As[(wm + f * 16 + lrow) * 64 + pc[h]];
#pragma unroll
      for (int f = 0; f < 4; ++f)
        b[f] = *(const bf16x8*)&Bs[(wn + f * 16 + lrow) * 64 + pc[h]];
#pragma unroll
      for (int fm = 0; fm < MF; ++fm)
#pragma unroll
        for (int fn = 0; fn < 4; ++fn)
          acc[fm][fn] = __builtin_amdgcn_mfma_f32_16x16x32_bf16(
              a[fm], b[fn], acc[fm][fn], 0, 0, 0);
    }
    __syncthreads();
  }
#pragma unroll
  for (int fm = 0; fm < MF; ++fm) {
    long pg   = tm * (BMT / 16) + (wm >> 4) + fm;
    long row0 = tm * BMT + wm + fm * 16 + quad * 4;
#pragma unroll
    for (int fn = 0; fn < 4; ++fn) {
      long col = tn * BN + wn + fn * 16 + lrow;
      float fx = Fx[pg * 512 + col] + bfb[col];
      float t = 0.f;
#pragma unroll
      for (int r = 0; r < 4; ++r)
        t += sig_(fx + acc[fm][fn][r]) * bf2f(Cbf[(row0 + r) * 512 + col]);
      t += __shfl_xor(t, 16, 64);
      t += __shfl_xor(t, 32, 64);
      if (quad == 0) Fpart[pg * 512 + col] = t;
    }
  }
}

// ---- wave-per-dot kernel (level-1 gates) -----------------------------------
__global__ void k_dot_bb(const uint16_t* __restrict__ A, int lda,
                         const uint16_t* __restrict__ B, int ldb,
                         float* __restrict__ C, int ldc,
                         int M, int N, int K) {
  int wid  = (int)((blockIdx.x * (long)blockDim.x + threadIdx.x) >> 6);
  int lane = threadIdx.x & 63;
  if (wid >= M * N) return;
  int m = wid / N, n = wid - m * N;
  const uint16_t* a = A + (long)m * lda;
  const uint16_t* b = B + (long)n * ldb;
  int per = K >> 6, k0 = lane * per;
  float s = 0.f;
  for (int j = 0; j < per; j += 4) {
    ushort4 av = *(const ushort4*)(a + k0 + j);
    ushort4 bv = *(const ushort4*)(b + k0 + j);
    s += bf2f(av.x) * bf2f(bv.x) + bf2f(av.y) * bf2f(bv.y)
       + bf2f(av.z) * bf2f(bv.z) + bf2f(av.w) * bf2f(bv.w);
  }
#pragma unroll
  for (int off = 32; off; off >>= 1) s += __shfl_xor(s, off, 64);
  if (lane == 0) C[(long)m * ldc + n] = s;
}

// ---- merged root dots: gates (bf16, M=1 N=1536 K=1024) + Fc (f32) ----------
__global__ void k_dot_merge(const uint16_t* __restrict__ xhC,
                            const uint16_t* __restrict__ Wg,
                            float* __restrict__ Gf,
                            const float* __restrict__ CupA,
                            const float* __restrict__ WfF,
                            float* __restrict__ Fc) {
  int wid  = (int)((blockIdx.x * (long)blockDim.x + threadIdx.x) >> 6);
  int lane = threadIdx.x & 63;
  if (wid < 1536) {                      // root gate dot: n = wid, K=1024
    const uint16_t* a = xhC;
    const uint16_t* b = Wg + (long)wid * 1024;
    int k0 = lane * 16;
    float s = 0.f;
#pragma unroll
    for (int j = 0; j < 16; j += 4) {
      ushort4 av = *(const ushort4*)(a + k0 + j);
      ushort4 bv = *(const ushort4*)(b + k0 + j);
      s += bf2f(av.x) * bf2f(bv.x) + bf2f(av.y) * bf2f(bv.y)
         + bf2f(av.z) * bf2f(bv.z) + bf2f(av.w) * bf2f(bv.w);
    }
#pragma unroll
    for (int off = 32; off; off >>= 1) s += __shfl_xor(s, off, 64);
    if (lane == 0) Gf[wid] = s;
  } else {                               // Fc: m<16, n<512, K=512, fp32
    int w2 = wid - 1536;
    if (w2 >= 16 * 512) return;
    int m = w2 >> 9, n = w2 & 511;
    const float* a = CupA + (long)m * 512;
    const float* b = WfF + (long)n * 1024;
    int k0 = lane * 8;
    float s = 0.f;
#pragma unroll
    for (int j = 0; j < 8; j += 4) {
      float4 av = *(const float4*)(a + k0 + j);
      float4 bv = *(const float4*)(b + k0 + j);
      s += av.x * bv.x + av.y * bv.y + av.z * bv.z + av.w * bv.w;
    }
#pragma unroll
    for (int off = 32; off; off >>= 1) s += __shfl_xor(s, off, 64);
    if (lane == 0) Fc[(long)m * 512 + n] = s;
  }
}

// ---- level-1 tail: final (16 nodes) + h_sum + root xh pack, one block ------
__global__ __launch_bounds__(1024)
void k_lvl1_tail(const float* __restrict__ G,
                 const float* __restrict__ Fpart,
                 const float* __restrict__ bi,
                 const float* __restrict__ bo,
                 const float* __restrict__ bu,
                 float* __restrict__ Cv,               // CupA (16x512)
                 const uint16_t* __restrict__ xroot,   // Xbf row 0
                 uint16_t* __restrict__ xh) {          // xhC row 0 pack
  __shared__ float Hl[16 * 512];                       // 32 KB
  const int tid = threadIdx.x;
#pragma unroll
  for (int it = 0; it < 2; ++it) {
    int idx = it * 1024 + tid;
    int p = idx >> 7, hq = (idx & 127) << 2;
    const float* g = G + (long)p * 1536;
    float4 gi = *(const float4*)(g + hq);
    float4 go = *(const float4*)(g + 512 + hq);
    float4 gu = *(const float4*)(g + 1024 + hq);
    float4 b_i = *(const float4*)(bi + hq);
    float4 b_o = *(const float4*)(bo + hq);
    float4 b_u = *(const float4*)(bu + hq);
    float4 fp = *(const float4*)(Fpart + (long)p * 512 + hq);
    const float* gip = &gi.x; const float* gop = &go.x;
    const float* gup = &gu.x; const float* bip = &b_i.x;
    const float* bop = &b_o.x; const float* bup = &b_u.x;
    const float* fpp = &fp.x;
    float4 hv, cv;
    float* hvp = &hv.x; float* cvp = &cv.x;
#pragma unroll
    for (int j = 0; j < 4; ++j) {
      float iv = sig_(gip[j] + bip[j]);
      float ov = sig_(gop[j] + bop[j]);
      float uv = tanh_(gup[j] + bup[j]);
      float c  = iv * uv + fpp[j];
      cvp[j] = c;
      hvp[j] = ov * tanh_(c);
    }
    *(float4*)(Cv + (long)p * 512 + hq) = cv;
    *(float4*)(&Hl[p * 512 + hq]) = hv;
  }
  __syncthreads();
  if (tid < 128) {
    int hq = tid << 2;
    float4 s = {0.f, 0.f, 0.f, 0.f};
#pragma unroll
    for (int b = 0; b < 16; ++b) {
      float4 v = *(const float4*)(&Hl[b * 512 + hq]);
      s.x += v.x; s.y += v.y; s.z += v.z; s.w += v.w;
    }
    *(ushort4*)(xh + hq) = *(const ushort4*)(xroot + hq);
    ushort4 hw = {f2bf(s.x), f2bf(s.y), f2bf(s.z), f2bf(s.w)};
    *(ushort4*)(xh + 512 + hq) = hw;
  }
}

// ---- fused root tail: combine (16 children) + final, 1 block, 128 thr ------
__global__ void k_root_tail(const float* __restrict__ Fc,
                            const float* __restrict__ Fx,
                            const float* __restrict__ bfb,
                            const float* __restrict__ Cc,
                            const float* __restrict__ G,
                            const float* __restrict__ bi,
                            const float* __restrict__ bo,
                            const float* __restrict__ bu,
                            float* __restrict__ H, float* __restrict__ Cv) {
  int hq = (threadIdx.x & 127) << 2;
  float4 fxv = *(const float4*)(Fx + hq);
  float4 bfv = *(const float4*)(bfb + hq);
  float fx0 = fxv.x + bfv.x, fx1 = fxv.y + bfv.y;
  float fx2 = fxv.z + bfv.z, fx3 = fxv.w + bfv.w;
  float a0 = 0.f, a1 = 0.f, a2 = 0.f, a3 = 0.f;
#pragma unroll 4
  for (int b = 0; b < 16; ++b) {
    float4 f = *(const float4*)(Fc + (long)b * 512 + hq);
    float4 c = *(const float4*)(Cc + (long)b * 512 + hq);
    a0 += sig_(fx0 + f.x) * c.x;
    a1 += sig_(fx1 + f.y) * c.y;
    a2 += sig_(fx2 + f.z) * c.z;
    a3 += sig_(fx3 + f.w) * c.w;
  }
  float fpp[4] = {a0, a1, a2, a3};
  float4 gi = *(const float4*)(G + hq);
  float4 go = *(const float4*)(G + 512 + hq);
  float4 gu = *(const float4*)(G + 1024 + hq);
  float4 b_i = *(const float4*)(bi + hq);
  float4 b_o = *(const float4*)(bo + hq);
  float4 b_u = *(const float4*)(bu + hq);
  const float* gip = &gi.x; const float* gop = &go.x; const float* gup = &gu.x;
  const float* bip = &b_i.x; const float* bop = &b_o.x; const float* bup = &b_u.x;
  float4 hv, cv;
  float* hvp = &hv.x; float* cvp = &cv.x;
#pragma unroll
  for (int j = 0; j < 4; ++j) {
    float iv = sig_(gip[j] + bip[j]);
    float ov = sig_(gop[j] + bop[j]);
    float uv = tanh_(gup[j] + bup[j]);
    float c  = iv * uv + fpp[j];
    cvp[j] = c;
    hvp[j] = ov * tanh_(c);
  }
  *(float4*)(H  + hq) = hv;
  *(float4*)(Cv + hq) = cv;
}

// ---------------------------------------------------------------------------
extern "C" void kernel_launch(void* const* d_in, const int* in_sizes, int n_in,
                              void* d_out, int out_size, void* d_ws, size_t ws_size,
                              hipStream_t stream) {
  const float* x    = (const float*)d_in[0];
  const float* wi_w = (const float*)d_in[1];
  const float* wi_b = (const float*)d_in[2];
  const float* wf_w = (const float*)d_in[3];
  const float* wf_b = (const float*)d_in[4];
  const float* wo_w = (const float*)d_in[5];
  const float* wo_b = (const float*)d_in[6];
  const float* wu_w = (const float*)d_in[7];
  const float* wu_b = (const float*)d_in[8];
  (void)in_sizes; (void)n_in; (void)out_size; (void)ws_size;

  static const long offs[5] = {0, 1, 17, 273, 4369};
  const long NTOT = 69905;

  // ---- workspace ----
  char* ws = (char*)d_ws;
  size_t off = 0;
  auto alloc = [&](size_t bytes) -> void* {
    void* p = ws + off;
    off += (bytes + 255) & ~(size_t)255;
    return p;
  };
  uint16_t* Xbf   = (uint16_t*)alloc(NTOT * 512 * 2);
  uint16_t* Wgw   = (uint16_t*)alloc((size_t)2048 * 1024 * 2);
  uint16_t* Wg    = Wgw;
  uint16_t* Wf    = Wgw + (size_t)1536 * 1024;
  float*    FxAll = (float*)alloc((size_t)4480 * 512 * 4);
  uint16_t* Cbf   = (uint16_t*)alloc((size_t)65536 * 512 * 2);
  uint16_t* CbfU  = (uint16_t*)alloc((size_t)4096 * 512 * 2);
  uint16_t* CbfU2 = (uint16_t*)alloc((size_t)256 * 512 * 2);
  uint16_t* xhA   = (uint16_t*)alloc((size_t)4096 * 1024 * 2);
  uint16_t* xhB   = (uint16_t*)alloc((size_t)256 * 1024 * 2);
  uint16_t* xhC   = (uint16_t*)alloc((size_t)16 * 1024 * 2);
  float*    Fpart = (float*)alloc((size_t)4096 * 512 * 4);
  float*    Gf    = (float*)alloc((size_t)16 * 1536 * 4);
  float*    Fc    = (float*)alloc((size_t)16 * 512 * 4);
  float*    CupA  = (float*)alloc((size_t)16 * 512 * 4);

  // ---- merged convert: all x + 4 weight matrices ----
  {
    long n4x = NTOT * 512 / 4;
    k_conv_all<<<8192, 256, 0, stream>>>(
        (const float4*)x, (ushort4*)Xbf, n4x,
        (const float4*)wi_w, (const float4*)wo_w,
        (const float4*)wu_w, (const float4*)wf_w, (ushort4*)Wgw);
  }

  // ---- Fx for all upper levels (node ids 0..4368, pad to 4480) ----
  {
    dim3 grid(35, 4);
    k_gemm_bt<<<grid, 256, 0, stream>>>(Xbf, 512, Wf, 1024, FxAll, 512, 512);
  }

  // ---- leaf level (M=65536, K=512): MF=4, nTm=512 ----
  k_level<false, 4><<<4096, 256, 0, stream>>>(
      Xbf + offs[4] * 512, 512, 512, Wg, wi_b, wo_b, wu_b, nullptr,
      Cbf, Xbf + offs[3] * 512, xhA);
  k_fc_combine<4><<<2048, 256, 0, stream>>>(Cbf, Wf + 512, 1024,
                                            FxAll + offs[3] * 512, wf_b, Fpart);

  // ---- level 3 (M=4096, K=1024): MF=2 (BM=64), nTm=64 -> 512 blocks ----
  k_level<true, 2><<<512, 256, 0, stream>>>(
      xhA, 1024, 1024, Wg, wi_b, wo_b, wu_b, Fpart,
      CbfU, Xbf + offs[2] * 512, xhB);
  k_fc_combine<2><<<256, 256, 0, stream>>>(CbfU, Wf + 512, 1024,
                                           FxAll + offs[2] * 512, wf_b, Fpart);

  // ---- level 2 (M=256, K=1024): MF=2, nTm=4 -> 32 blocks (plain map) ----
  k_level<true, 2><<<32, 256, 0, stream>>>(
      xhB, 1024, 1024, Wg, wi_b, wo_b, wu_b, Fpart,
      CbfU2, Xbf + offs[1] * 512, xhC);
  k_fc_combine<2><<<16, 256, 0, stream>>>(CbfU2, Wf + 512, 1024,
                                          FxAll + offs[1] * 512, wf_b, Fpart);

  // ---- level 1 (n=16): gates + fused tail (final+hsum+root pack) ----
  {
    long waves = 16L * 1536;
    k_dot_bb<<<(int)((waves * 64 + 255) / 256), 256, 0, stream>>>(
        xhC, 1024, Wg, 1024, Gf, 1536, 16, 1536, 1024);
    k_lvl1_tail<<<1, 1024, 0, stream>>>(Gf, Fpart, wi_b, wo_b, wu_b,
                                        CupA, Xbf + offs[0] * 512, xhC);
  }

  // ---- level 0 (root): merged gate-dot + Fc-dot, then fused tail ----
  {
    long waves = 1536 + 16L * 512;       // 9728 waves = 2432 blocks exactly
    k_dot_merge<<<(int)(waves / 4), 256, 0, stream>>>(
        xhC, Wg, Gf, CupA, wf_w + 512, Fc);
  }
  k_root_tail<<<1, 128, 0, stream>>>(Fc, FxAll, wf_b, CupA, Gf,
                                     wi_b, wo_b, wu_b,
                                     (float*)d_out, (float*)d_out + 512);
}

// Round 8
// 471.758 us; speedup vs baseline: 1.3141x; 1.0490x over previous
//
#include <hip/hip_runtime.h>
#include <stdint.h>
#include <stddef.h>

// ---------------------------------------------------------------------------
// CSTreeLSTM on gfx950. Levels 1,16,256,4096,65536 (x offsets 0,1,17,273,4369).
// Round 16: launch-overlap merges of independent dispatches.
//  - k_leaf_fx: leaf k_level (4096 blks) + FxAll gemm_bt (140 blks) in one
//    launch (both depend only on conv; FxAll hides under leaf's 137us).
//  - k_fcdot: lvl2 fc_combine (16 blks) + lvl1 gate dots (6144 blks) merged
//    (independent: fc->Fpart->lvl1_tail, dot->Gf; both ready after lvl2).
// Core GEMM bodies byte-identical to round-15 (2-phase, T2 swizzle both-
// sides, conflicts=0, 3 blocks/CU). 12 -> 10 launches.
// ---------------------------------------------------------------------------

typedef __bf16 bf16x8 __attribute__((ext_vector_type(8)));
typedef float  f32x4  __attribute__((ext_vector_type(4)));
typedef void __attribute__((address_space(3))) lds_void_t;
typedef void __attribute__((address_space(1))) gbl_void_t;

__device__ __forceinline__ uint16_t f2bf(float f) {
  union { __bf16 b; uint16_t u; } v;
  v.b = (__bf16)f;              // RTNE, compiler emits v_cvt_pk_bf16_f32
  return v.u;
}
__device__ __forceinline__ float bf2f(uint16_t u) {
  union { uint32_t u; float f; } v; v.u = (uint32_t)u << 16;
  return v.f;
}
// native v_rcp_f32 (~1 ulp) -- error budget is huge
__device__ __forceinline__ float sig_(float x) {
  return __builtin_amdgcn_rcpf(1.0f + __expf(-x));
}
// tanh(x) = 2/(1+exp(-2x)) - 1 : mul+exp+add+rcp+fma, no clamp, inf-safe
__device__ __forceinline__ float tanh_(float x) {
  return __builtin_fmaf(2.f,
      __builtin_amdgcn_rcpf(1.f + __expf(-2.f * x)), -1.f);
}

// ---- merged convert: all x rows + 4 weight matrices ------------------------
__global__ void k_conv_all(const float4* __restrict__ x,
                           ushort4* __restrict__ xdst, long n4x,
                           const float4* __restrict__ w0,
                           const float4* __restrict__ w1,
                           const float4* __restrict__ w2,
                           const float4* __restrict__ w3,
                           ushort4* __restrict__ wdst) {
  const long per4 = (long)512 * 1024 / 4;
  const long total = n4x + 4 * per4;
  long i = blockIdx.x * (long)blockDim.x + threadIdx.x;
  long stride = (long)gridDim.x * blockDim.x;
  for (; i < total; i += stride) {
    float4 v;
    ushort4* d;
    if (i < n4x) {
      v = x[i];
      d = xdst + i;
    } else {
      long j = i - n4x;
      long seg = j / per4, off2 = j - seg * per4;
      const float4* s = (seg == 0) ? w0 : (seg == 1) ? w1
                       : (seg == 2) ? w2 : w3;
      v = s[off2];
      d = wdst + j;
    }
    ushort4 r;
    r.x = f2bf(v.x); r.y = f2bf(v.y); r.z = f2bf(v.z); r.w = f2bf(v.w);
    *d = r;
  }
}

#define BM 128
#define BN 128
#define BK 32

// ---- merged leaf k_level + FxAll gemm_bt -----------------------------------
// Blocks [0,4096): leaf level (M=65536, K=512, HAS_F=false, MF=4, nTm=512
// hardcoded for the XCD swizzle). Blocks [4096,4236): FxAll = Xbf(4480x512)
// x Wf(512x1024,rows 0..511)^T -> FxAll (35x4 tile grid). Shared 40KB pool.
__global__ __launch_bounds__(256, 3)
void k_leaf_fx(const uint16_t* __restrict__ Xleaf,       // Xbf + offs4*512
               const uint16_t* __restrict__ Wg,
               const float* __restrict__ bi, const float* __restrict__ bo,
               const float* __restrict__ bu,
               uint16_t* __restrict__ Cbf,
               const uint16_t* __restrict__ Xnext,       // Xbf + offs3*512
               uint16_t* __restrict__ xh_next,           // xhA
               const uint16_t* __restrict__ Xbf,         // for FxAll A
               const uint16_t* __restrict__ Wf,          // FxAll B
               float* __restrict__ FxAll) {
  __shared__ uint16_t smem[20480];                       // 40 KB pool
  const int tid = threadIdx.x, lane = tid & 63, wave = tid >> 6;
  const int lrow = lane & 15, quad = lane >> 4;

  if (blockIdx.x < 4096) {
    // ---------------- leaf k_level (round-15 MF=4 body, verbatim) ----------
    uint16_t* As = smem;                 // 128*64
    uint16_t* Bs = smem + 8192;          // 192*64
    const int wm = (wave >> 1) * 64, wn = (wave & 1) * 32;
    long tm, tn;
    {
      const int nTm = 512;               // hardcoded (grid carries +140)
      int b = blockIdx.x;
      int x = b & 7, j = b >> 3, per = nTm >> 3;
      tn = j & 7; tm = (long)x * per + (j >> 3);
    }
    f32x4 acc[3][4][2] = {};
    const int srow = lane >> 3;
    const int scol = (((lane & 7) ^ srow) << 3);
    const int rsw = lrow & 7;
    const int pc[2] = { ((0 + quad) ^ rsw) << 3, ((4 + quad) ^ rsw) << 3 };

    for (int k0 = 0; k0 < 512; k0 += 64) {
#pragma unroll
      for (int j = 0; j < 4; ++j) {
        int grp = wave * 4 + j;
        int row = grp * 8 + srow;
        const uint16_t* gp = Xleaf + (tm * 128 + row) * 512L + k0 + scol;
        __builtin_amdgcn_global_load_lds((gbl_void_t*)(uintptr_t)gp,
            (lds_void_t*)&As[grp * 512], 16, 0, 0);
      }
#pragma unroll
      for (int j = 0; j < 6; ++j) {
        int cc = wave * 6 + j;
        int g  = cc >> 3;
        long grow = (long)g * 512 + tn * 64 + (cc & 7) * 8 + srow;
        const uint16_t* gp = Wg + grow * 1024 + k0 + scol;
        __builtin_amdgcn_global_load_lds((gbl_void_t*)(uintptr_t)gp,
            (lds_void_t*)&Bs[cc * 512], 16, 0, 0);
      }
      __syncthreads();
#pragma unroll
      for (int h = 0; h < 2; ++h) {
        bf16x8 a[4];
#pragma unroll
        for (int f = 0; f < 4; ++f)
          a[f] = *(const bf16x8*)&As[(wm + f * 16 + lrow) * 64 + pc[h]];
#pragma unroll
        for (int g = 0; g < 3; ++g) {
          bf16x8 b0 = *(const bf16x8*)&Bs[(g * 64 + wn + lrow) * 64 + pc[h]];
          bf16x8 b1 = *(const bf16x8*)&Bs[(g * 64 + wn + 16 + lrow) * 64 +
                                          pc[h]];
#pragma unroll
          for (int fm = 0; fm < 4; ++fm) {
            acc[g][fm][0] = __builtin_amdgcn_mfma_f32_16x16x32_bf16(
                a[fm], b0, acc[g][fm][0], 0, 0, 0);
            acc[g][fm][1] = __builtin_amdgcn_mfma_f32_16x16x32_bf16(
                a[fm], b1, acc[g][fm][1], 0, 0, 0);
          }
        }
      }
      __syncthreads();
    }
#pragma unroll
    for (int fn = 0; fn < 2; ++fn) {
      long col = tn * 64 + wn + fn * 16 + lrow;
      float biv = bi[col], bov = bo[col], buv = bu[col];
#pragma unroll
      for (int fm = 0; fm < 4; ++fm) {
        long row0 = tm * 128 + wm + fm * 16 + quad * 4;
        long pg   = tm * 8 + (wm >> 4) + fm;
        float hs = 0.f;
#pragma unroll
        for (int r = 0; r < 4; ++r) {
          long row = row0 + r;
          float iv = sig_(acc[0][fm][fn][r] + biv);
          float ov = sig_(acc[1][fm][fn][r] + bov);
          float uv = tanh_(acc[2][fm][fn][r] + buv);
          float c  = iv * uv;
          Cbf[row * 512 + col] = f2bf(c);
          hs += ov * tanh_(c);
        }
        hs += __shfl_xor(hs, 16, 64);
        hs += __shfl_xor(hs, 32, 64);
        if (quad == 0) {
          xh_next[pg * 1024 + col]       = Xnext[pg * 512 + col];
          xh_next[pg * 1024 + 512 + col] = f2bf(hs);
        }
      }
    }
  } else {
    // ---------------- FxAll gemm_bt (round-15 body, bid remapped) ----------
    uint16_t* As = smem;                 // 128*32
    uint16_t* Bs = smem + 4096;          // 128*32
    const int wm = (wave >> 1) * 64, wn = (wave & 1) * 64;
    int bid2 = (int)blockIdx.x - 4096;
    const long tm = bid2 % 35, tn = bid2 / 35;
    f32x4 acc[4][4] = {};
    const int srow2 = lane >> 2, scol2 = (lane & 3) * 8;
    for (int k0 = 0; k0 < 512; k0 += BK) {
#pragma unroll
      for (int i = 0; i < 2; ++i) {
        int row = i * 64 + wave * 16 + srow2;
        const uint16_t* gp = Xbf + (tm * BM + row) * 512L + k0 + scol2;
        __builtin_amdgcn_global_load_lds((gbl_void_t*)(uintptr_t)gp,
            (lds_void_t*)&As[i * 2048 + wave * 512], 16, 0, 0);
      }
#pragma unroll
      for (int i = 0; i < 2; ++i) {
        int row = i * 64 + wave * 16 + srow2;
        const uint16_t* gp = Wf + (tn * BN + row) * 1024L + k0 + scol2;
        __builtin_amdgcn_global_load_lds((gbl_void_t*)(uintptr_t)gp,
            (lds_void_t*)&Bs[i * 2048 + wave * 512], 16, 0, 0);
      }
      __syncthreads();
      bf16x8 a[4], b[4];
#pragma unroll
      for (int f = 0; f < 4; ++f)
        a[f] = *(const bf16x8*)&As[(wm + f * 16 + lrow) * BK + quad * 8];
#pragma unroll
      for (int f = 0; f < 4; ++f)
        b[f] = *(const bf16x8*)&Bs[(wn + f * 16 + lrow) * BK + quad * 8];
#pragma unroll
      for (int fm = 0; fm < 4; ++fm)
#pragma unroll
        for (int fn = 0; fn < 4; ++fn)
          acc[fm][fn] = __builtin_amdgcn_mfma_f32_16x16x32_bf16(
              a[fm], b[fn], acc[fm][fn], 0, 0, 0);
      __syncthreads();
    }
#pragma unroll
    for (int fm = 0; fm < 4; ++fm)
#pragma unroll
      for (int fn = 0; fn < 4; ++fn) {
        long col  = tn * BN + wn + fn * 16 + lrow;
        long row0 = tm * BM + wm + fm * 16 + quad * 4;
#pragma unroll
        for (int r = 0; r < 4; ++r)
          FxAll[(row0 + r) * 512 + col] = acc[fm][fn][r];
      }
  }
}

// ---- fused level kernel (MF-templated: BM = MF*32) -------------------------
template <bool HAS_F, int MF>
__global__ __launch_bounds__(256, 3)
void k_level(const uint16_t* __restrict__ A, int lda, int K,
             const uint16_t* __restrict__ Wg,
             const float* __restrict__ bi, const float* __restrict__ bo,
             const float* __restrict__ bu,
             const float* __restrict__ Fpart,
             uint16_t* __restrict__ Cbf,
             const uint16_t* __restrict__ Xnext,
             uint16_t* __restrict__ xh_next) {
  constexpr int BMT = MF * 32;
  __shared__ uint16_t As[BMT * 64];
  __shared__ uint16_t Bs[192 * 64];
  const int tid = threadIdx.x, lane = tid & 63, wave = tid >> 6;
  const int lrow = lane & 15, quad = lane >> 4;
  const int wm = (wave >> 1) * (MF * 16), wn = (wave & 1) * 32;

  long tm, tn;
  {
    const int nTm = (int)(gridDim.x >> 3);
    int b = blockIdx.x;
    if ((nTm & 7) == 0) {
      int x = b & 7, j = b >> 3, per = nTm >> 3;
      tn = j & 7; tm = (long)x * per + (j >> 3);
    } else { tm = b >> 3; tn = b & 7; }
  }

  f32x4 acc[3][MF][2] = {};

  const int srow = lane >> 3;
  const int scol = (((lane & 7) ^ srow) << 3);
  const int rsw = lrow & 7;
  const int pc[2] = { ((0 + quad) ^ rsw) << 3, ((4 + quad) ^ rsw) << 3 };

  for (int k0 = 0; k0 < K; k0 += 64) {
#pragma unroll
    for (int j = 0; j < MF; ++j) {
      int grp = wave * MF + j;
      int row = grp * 8 + srow;
      const uint16_t* gp = A + (tm * BMT + row) * (long)lda + k0 + scol;
      __builtin_amdgcn_global_load_lds((gbl_void_t*)(uintptr_t)gp,
          (lds_void_t*)&As[grp * 512], 16, 0, 0);
    }
#pragma unroll
    for (int j = 0; j < 6; ++j) {
      int cc = wave * 6 + j;
      int g  = cc >> 3;
      long grow = (long)g * 512 + tn * 64 + (cc & 7) * 8 + srow;
      const uint16_t* gp = Wg + grow * 1024 + k0 + scol;
      __builtin_amdgcn_global_load_lds((gbl_void_t*)(uintptr_t)gp,
          (lds_void_t*)&Bs[cc * 512], 16, 0, 0);
    }
    __syncthreads();

#pragma unroll
    for (int h = 0; h < 2; ++h) {
      bf16x8 a[MF];
#pragma unroll
      for (int f = 0; f < MF; ++f)
        a[f] = *(const bf16x8*)&As[(wm + f * 16 + lrow) * 64 + pc[h]];
#pragma unroll
      for (int g = 0; g < 3; ++g) {
        bf16x8 b0 = *(const bf16x8*)&Bs[(g * 64 + wn + lrow) * 64 + pc[h]];
        bf16x8 b1 = *(const bf16x8*)&Bs[(g * 64 + wn + 16 + lrow) * 64 +
                                        pc[h]];
#pragma unroll
        for (int fm = 0; fm < MF; ++fm) {
          acc[g][fm][0] = __builtin_amdgcn_mfma_f32_16x16x32_bf16(
              a[fm], b0, acc[g][fm][0], 0, 0, 0);
          acc[g][fm][1] = __builtin_amdgcn_mfma_f32_16x16x32_bf16(
              a[fm], b1, acc[g][fm][1], 0, 0, 0);
        }
      }
    }
    __syncthreads();
  }

#pragma unroll
  for (int fn = 0; fn < 2; ++fn) {
    long col = tn * 64 + wn + fn * 16 + lrow;
    float biv = bi[col], bov = bo[col], buv = bu[col];
#pragma unroll
    for (int fm = 0; fm < MF; ++fm) {
      long row0 = tm * BMT + wm + fm * 16 + quad * 4;
      long pg   = tm * (BMT / 16) + (wm >> 4) + fm;
      float hs = 0.f;
#pragma unroll
      for (int r = 0; r < 4; ++r) {
        long row = row0 + r;
        float iv = sig_(acc[0][fm][fn][r] + biv);
        float ov = sig_(acc[1][fm][fn][r] + bov);
        float uv = tanh_(acc[2][fm][fn][r] + buv);
        float c  = iv * uv;
        if (HAS_F) c += Fpart[row * 512 + col];
        Cbf[row * 512 + col] = f2bf(c);
        hs += ov * tanh_(c);
      }
      hs += __shfl_xor(hs, 16, 64);
      hs += __shfl_xor(hs, 32, 64);
      if (quad == 0) {
        xh_next[pg * 1024 + col]       = Xnext[pg * 512 + col];
        xh_next[pg * 1024 + 512 + col] = f2bf(hs);
      }
    }
  }
}

// ---- fc GEMM + fused forget-combine (MF-templated) -------------------------
template <int MF>
__global__ __launch_bounds__(256, 3)
void k_fc_combine(const uint16_t* __restrict__ Cbf,
                  const uint16_t* __restrict__ Wfc, int ldb,
                  const float* __restrict__ Fx,
                  const float* __restrict__ bfb,
                  float* __restrict__ Fpart) {
  constexpr int BMT = MF * 32;
  __shared__ uint16_t As[BMT * 64];
  __shared__ uint16_t Bs[128 * 64];
  const int tid = threadIdx.x, lane = tid & 63, wave = tid >> 6;
  const int lrow = lane & 15, quad = lane >> 4;
  const int wm = (wave >> 1) * (MF * 16), wn = (wave & 1) * 64;
  long tm, tn;
  {
    const int nTm = (int)(gridDim.x >> 2);
    int b = blockIdx.x;
    if ((nTm & 7) == 0) {
      int x = b & 7, j = b >> 3, per = nTm >> 3;
      tn = j & 3; tm = (long)x * per + (j >> 2);
    } else { tm = b >> 2; tn = b & 3; }
  }
  const int lda = 512;
  f32x4 acc[MF][4] = {};

  const int srow = lane >> 3;
  const int scol = (((lane & 7) ^ srow) << 3);
  const int rsw = lrow & 7;
  const int pc[2] = { ((0 + quad) ^ rsw) << 3, ((4 + quad) ^ rsw) << 3 };

  for (int k0 = 0; k0 < 512; k0 += 64) {
#pragma unroll
    for (int j = 0; j < MF; ++j) {
      int grp = wave * MF + j;
      int row = grp * 8 + srow;
      const uint16_t* gp = Cbf + (tm * BMT + row) * (long)lda + k0 + scol;
      __builtin_amdgcn_global_load_lds((gbl_void_t*)(uintptr_t)gp,
          (lds_void_t*)&As[grp * 512], 16, 0, 0);
    }
#pragma unroll
    for (int j = 0; j < 4; ++j) {
      int row = wave * 32 + j * 8 + srow;
      const uint16_t* gp = Wfc + (tn * BN + row) * (long)ldb + k0 + scol;
      __builtin_amdgcn_global_load_lds((gbl_void_t*)(uintptr_t)gp,
          (lds_void_t*)&Bs[(wave * 32 + j * 8) * 64], 16, 0, 0);
    }
    __syncthreads();
#pragma unroll
    for (int h = 0; h < 2; ++h) {
      bf16x8 a[MF], b[4];
#pragma unroll
      for (int f = 0; f < MF; ++f)
        a[f] = *(const bf16x8*)&As[(wm + f * 16 + lrow) * 64 + pc[h]];
#pragma unroll
      for (int f = 0; f < 4; ++f)
        b[f] = *(const bf16x8*)&Bs[(wn + f * 16 + lrow) * 64 + pc[h]];
#pragma unroll
      for (int fm = 0; fm < MF; ++fm)
#pragma unroll
        for (int fn = 0; fn < 4; ++fn)
          acc[fm][fn] = __builtin_amdgcn_mfma_f32_16x16x32_bf16(
              a[fm], b[fn], acc[fm][fn], 0, 0, 0);
    }
    __syncthreads();
  }
#pragma unroll
  for (int fm = 0; fm < MF; ++fm) {
    long pg   = tm * (BMT / 16) + (wm >> 4) + fm;
    long row0 = tm * BMT + wm + fm * 16 + quad * 4;
#pragma unroll
    for (int fn = 0; fn < 4; ++fn) {
      long col = tn * BN + wn + fn * 16 + lrow;
      float fx = Fx[pg * 512 + col] + bfb[col];
      float t = 0.f;
#pragma unroll
      for (int r = 0; r < 4; ++r)
        t += sig_(fx + acc[fm][fn][r]) * bf2f(Cbf[(row0 + r) * 512 + col]);
      t += __shfl_xor(t, 16, 64);
      t += __shfl_xor(t, 32, 64);
      if (quad == 0) Fpart[pg * 512 + col] = t;
    }
  }
}

// ---- merged lvl2 fc_combine (MF=2, 16 blocks) + lvl1 gate dots -------------
// Blocks [0,16): fc body (M=256, BMT=64, nTm=4 plain map). Blocks [16,6160):
// dot_bb waves for Gf = xhC(16x1024) x Wg(1536x1024)^T.
__global__ __launch_bounds__(256)
void k_fcdot(const uint16_t* __restrict__ Cbf,           // CbfU2
             const uint16_t* __restrict__ Wfc,           // Wf + 512
             const float* __restrict__ Fx,
             const float* __restrict__ bfb,
             float* __restrict__ Fpart,
             const uint16_t* __restrict__ xhC,
             const uint16_t* __restrict__ Wg,
             float* __restrict__ Gf) {
  __shared__ uint16_t smem[12288];                       // 24 KB (fc branch)
  const int tid = threadIdx.x, lane = tid & 63, wave = tid >> 6;
  if (blockIdx.x < 16) {
    uint16_t* As = smem;                 // 64*64
    uint16_t* Bs = smem + 4096;          // 128*64
    const int lrow = lane & 15, quad = lane >> 4;
    const int wm = (wave >> 1) * 32, wn = (wave & 1) * 64;
    int b = blockIdx.x;
    long tm = b >> 2, tn = b & 3;        // nTm=4 plain map
    f32x4 acc[2][4] = {};
    const int srow = lane >> 3;
    const int scol = (((lane & 7) ^ srow) << 3);
    const int rsw = lrow & 7;
    const int pc[2] = { ((0 + quad) ^ rsw) << 3, ((4 + quad) ^ rsw) << 3 };
    for (int k0 = 0; k0 < 512; k0 += 64) {
#pragma unroll
      for (int j = 0; j < 2; ++j) {
        int grp = wave * 2 + j;
        int row = grp * 8 + srow;
        const uint16_t* gp = Cbf + (tm * 64 + row) * 512L + k0 + scol;
        __builtin_amdgcn_global_load_lds((gbl_void_t*)(uintptr_t)gp,
            (lds_void_t*)&As[grp * 512], 16, 0, 0);
      }
#pragma unroll
      for (int j = 0; j < 4; ++j) {
        int row = wave * 32 + j * 8 + srow;
        const uint16_t* gp = Wfc + (tn * 128 + row) * 1024L + k0 + scol;
        __builtin_amdgcn_global_load_lds((gbl_void_t*)(uintptr_t)gp,
            (lds_void_t*)&Bs[(wave * 32 + j * 8) * 64], 16, 0, 0);
      }
      __syncthreads();
#pragma unroll
      for (int h = 0; h < 2; ++h) {
        bf16x8 a[2], bb[4];
#pragma unroll
        for (int f = 0; f < 2; ++f)
          a[f] = *(const bf16x8*)&As[(wm + f * 16 + lrow) * 64 + pc[h]];
#pragma unroll
        for (int f = 0; f < 4; ++f)
          bb[f] = *(const bf16x8*)&Bs[(wn + f * 16 + lrow) * 64 + pc[h]];
#pragma unroll
        for (int fm = 0; fm < 2; ++fm)
#pragma unroll
          for (int fn = 0; fn < 4; ++fn)
            acc[fm][fn] = __builtin_amdgcn_mfma_f32_16x16x32_bf16(
                a[fm], bb[fn], acc[fm][fn], 0, 0, 0);
      }
      __syncthreads();
    }
#pragma unroll
    for (int fm = 0; fm < 2; ++fm) {
      long pg   = tm * 4 + (wm >> 4) + fm;
      long row0 = tm * 64 + wm + fm * 16 + quad * 4;
#pragma unroll
      for (int fn = 0; fn < 4; ++fn) {
        long col = tn * 128 + wn + fn * 16 + lrow;
        float fx = Fx[pg * 512 + col] + bfb[col];
        float t = 0.f;
#pragma unroll
        for (int r = 0; r < 4; ++r)
          t += sig_(fx + acc[fm][fn][r]) * bf2f(Cbf[(row0 + r) * 512 + col]);
        t += __shfl_xor(t, 16, 64);
        t += __shfl_xor(t, 32, 64);
        if (quad == 0) Fpart[pg * 512 + col] = t;
      }
    }
  } else {
    // dot: wid in [0, 16*1536), m = wid/1536, n = wid%1536, K=1024
    int wid = (int)(((long)(blockIdx.x - 16) * 256 + tid) >> 6);
    if (wid >= 16 * 1536) return;
    int m = wid / 1536, n = wid - m * 1536;
    const uint16_t* a = xhC + (long)m * 1024;
    const uint16_t* b = Wg + (long)n * 1024;
    int k0 = lane * 16;
    float s = 0.f;
#pragma unroll
    for (int j = 0; j < 16; j += 4) {
      ushort4 av = *(const ushort4*)(a + k0 + j);
      ushort4 bv = *(const ushort4*)(b + k0 + j);
      s += bf2f(av.x) * bf2f(bv.x) + bf2f(av.y) * bf2f(bv.y)
         + bf2f(av.z) * bf2f(bv.z) + bf2f(av.w) * bf2f(bv.w);
    }
#pragma unroll
    for (int off = 32; off; off >>= 1) s += __shfl_xor(s, off, 64);
    if (lane == 0) Gf[(long)m * 1536 + n] = s;
  }
}

// ---- merged root dots: gates (bf16, M=1 N=1536 K=1024) + Fc (f32) ----------
__global__ void k_dot_merge(const uint16_t* __restrict__ xhC,
                            const uint16_t* __restrict__ Wg,
                            float* __restrict__ Gf,
                            const float* __restrict__ CupA,
                            const float* __restrict__ WfF,
                            float* __restrict__ Fc) {
  int wid  = (int)((blockIdx.x * (long)blockDim.x + threadIdx.x) >> 6);
  int lane = threadIdx.x & 63;
  if (wid < 1536) {
    const uint16_t* a = xhC;
    const uint16_t* b = Wg + (long)wid * 1024;
    int k0 = lane * 16;
    float s = 0.f;
#pragma unroll
    for (int j = 0; j < 16; j += 4) {
      ushort4 av = *(const ushort4*)(a + k0 + j);
      ushort4 bv = *(const ushort4*)(b + k0 + j);
      s += bf2f(av.x) * bf2f(bv.x) + bf2f(av.y) * bf2f(bv.y)
         + bf2f(av.z) * bf2f(bv.z) + bf2f(av.w) * bf2f(bv.w);
    }
#pragma unroll
    for (int off = 32; off; off >>= 1) s += __shfl_xor(s, off, 64);
    if (lane == 0) Gf[wid] = s;
  } else {
    int w2 = wid - 1536;
    if (w2 >= 16 * 512) return;
    int m = w2 >> 9, n = w2 & 511;
    const float* a = CupA + (long)m * 512;
    const float* b = WfF + (long)n * 1024;
    int k0 = lane * 8;
    float s = 0.f;
#pragma unroll
    for (int j = 0; j < 8; j += 4) {
      float4 av = *(const float4*)(a + k0 + j);
      float4 bv = *(const float4*)(b + k0 + j);
      s += av.x * bv.x + av.y * bv.y + av.z * bv.z + av.w * bv.w;
    }
#pragma unroll
    for (int off = 32; off; off >>= 1) s += __shfl_xor(s, off, 64);
    if (lane == 0) Fc[(long)m * 512 + n] = s;
  }
}

// ---- level-1 tail: final (16 nodes) + h_sum + root xh pack, one block ------
__global__ __launch_bounds__(1024)
void k_lvl1_tail(const float* __restrict__ G,
                 const float* __restrict__ Fpart,
                 const float* __restrict__ bi,
                 const float* __restrict__ bo,
                 const float* __restrict__ bu,
                 float* __restrict__ Cv,               // CupA (16x512)
                 const uint16_t* __restrict__ xroot,   // Xbf row 0
                 uint16_t* __restrict__ xh) {          // xhC row 0 pack
  __shared__ float Hl[16 * 512];                       // 32 KB
  const int tid = threadIdx.x;
#pragma unroll
  for (int it = 0; it < 2; ++it) {
    int idx = it * 1024 + tid;
    int p = idx >> 7, hq = (idx & 127) << 2;
    const float* g = G + (long)p * 1536;
    float4 gi = *(const float4*)(g + hq);
    float4 go = *(const float4*)(g + 512 + hq);
    float4 gu = *(const float4*)(g + 1024 + hq);
    float4 b_i = *(const float4*)(bi + hq);
    float4 b_o = *(const float4*)(bo + hq);
    float4 b_u = *(const float4*)(bu + hq);
    float4 fp = *(const float4*)(Fpart + (long)p * 512 + hq);
    const float* gip = &gi.x; const float* gop = &go.x;
    const float* gup = &gu.x; const float* bip = &b_i.x;
    const float* bop = &b_o.x; const float* bup = &b_u.x;
    const float* fpp = &fp.x;
    float4 hv, cv;
    float* hvp = &hv.x; float* cvp = &cv.x;
#pragma unroll
    for (int j = 0; j < 4; ++j) {
      float iv = sig_(gip[j] + bip[j]);
      float ov = sig_(gop[j] + bop[j]);
      float uv = tanh_(gup[j] + bup[j]);
      float c  = iv * uv + fpp[j];
      cvp[j] = c;
      hvp[j] = ov * tanh_(c);
    }
    *(float4*)(Cv + (long)p * 512 + hq) = cv;
    *(float4*)(&Hl[p * 512 + hq]) = hv;
  }
  __syncthreads();
  if (tid < 128) {
    int hq = tid << 2;
    float4 s = {0.f, 0.f, 0.f, 0.f};
#pragma unroll
    for (int b = 0; b < 16; ++b) {
      float4 v = *(const float4*)(&Hl[b * 512 + hq]);
      s.x += v.x; s.y += v.y; s.z += v.z; s.w += v.w;
    }
    *(ushort4*)(xh + hq) = *(const ushort4*)(xroot + hq);
    ushort4 hw = {f2bf(s.x), f2bf(s.y), f2bf(s.z), f2bf(s.w)};
    *(ushort4*)(xh + 512 + hq) = hw;
  }
}

// ---- fused root tail: combine (16 children) + final, 1 block, 128 thr ------
__global__ void k_root_tail(const float* __restrict__ Fc,
                            const float* __restrict__ Fx,
                            const float* __restrict__ bfb,
                            const float* __restrict__ Cc,
                            const float* __restrict__ G,
                            const float* __restrict__ bi,
                            const float* __restrict__ bo,
                            const float* __restrict__ bu,
                            float* __restrict__ H, float* __restrict__ Cv) {
  int hq = (threadIdx.x & 127) << 2;
  float4 fxv = *(const float4*)(Fx + hq);
  float4 bfv = *(const float4*)(bfb + hq);
  float fx0 = fxv.x + bfv.x, fx1 = fxv.y + bfv.y;
  float fx2 = fxv.z + bfv.z, fx3 = fxv.w + bfv.w;
  float a0 = 0.f, a1 = 0.f, a2 = 0.f, a3 = 0.f;
#pragma unroll 4
  for (int b = 0; b < 16; ++b) {
    float4 f = *(const float4*)(Fc + (long)b * 512 + hq);
    float4 c = *(const float4*)(Cc + (long)b * 512 + hq);
    a0 += sig_(fx0 + f.x) * c.x;
    a1 += sig_(fx1 + f.y) * c.y;
    a2 += sig_(fx2 + f.z) * c.z;
    a3 += sig_(fx3 + f.w) * c.w;
  }
  float fpp[4] = {a0, a1, a2, a3};
  float4 gi = *(const float4*)(G + hq);
  float4 go = *(const float4*)(G + 512 + hq);
  float4 gu = *(const float4*)(G + 1024 + hq);
  float4 b_i = *(const float4*)(bi + hq);
  float4 b_o = *(const float4*)(bo + hq);
  float4 b_u = *(const float4*)(bu + hq);
  const float* gip = &gi.x; const float* gop = &go.x; const float* gup = &gu.x;
  const float* bip = &b_i.x; const float* bop = &b_o.x; const float* bup = &b_u.x;
  float4 hv, cv;
  float* hvp = &hv.x; float* cvp = &cv.x;
#pragma unroll
  for (int j = 0; j < 4; ++j) {
    float iv = sig_(gip[j] + bip[j]);
    float ov = sig_(gop[j] + bop[j]);
    float uv = tanh_(gup[j] + bup[j]);
    float c  = iv * uv + fpp[j];
    cvp[j] = c;
    hvp[j] = ov * tanh_(c);
  }
  *(float4*)(H  + hq) = hv;
  *(float4*)(Cv + hq) = cv;
}

// ---------------------------------------------------------------------------
extern "C" void kernel_launch(void* const* d_in, const int* in_sizes, int n_in,
                              void* d_out, int out_size, void* d_ws, size_t ws_size,
                              hipStream_t stream) {
  const float* x    = (const float*)d_in[0];
  const float* wi_w = (const float*)d_in[1];
  const float* wi_b = (const float*)d_in[2];
  const float* wf_w = (const float*)d_in[3];
  const float* wf_b = (const float*)d_in[4];
  const float* wo_w = (const float*)d_in[5];
  const float* wo_b = (const float*)d_in[6];
  const float* wu_w = (const float*)d_in[7];
  const float* wu_b = (const float*)d_in[8];
  (void)in_sizes; (void)n_in; (void)out_size; (void)ws_size;

  static const long offs[5] = {0, 1, 17, 273, 4369};
  const long NTOT = 69905;

  // ---- workspace ----
  char* ws = (char*)d_ws;
  size_t off = 0;
  auto alloc = [&](size_t bytes) -> void* {
    void* p = ws + off;
    off += (bytes + 255) & ~(size_t)255;
    return p;
  };
  uint16_t* Xbf   = (uint16_t*)alloc(NTOT * 512 * 2);
  uint16_t* Wgw   = (uint16_t*)alloc((size_t)2048 * 1024 * 2);
  uint16_t* Wg    = Wgw;
  uint16_t* Wf    = Wgw + (size_t)1536 * 1024;
  float*    FxAll = (float*)alloc((size_t)4480 * 512 * 4);
  uint16_t* Cbf   = (uint16_t*)alloc((size_t)65536 * 512 * 2);
  uint16_t* CbfU  = (uint16_t*)alloc((size_t)4096 * 512 * 2);
  uint16_t* CbfU2 = (uint16_t*)alloc((size_t)256 * 512 * 2);
  uint16_t* xhA   = (uint16_t*)alloc((size_t)4096 * 1024 * 2);
  uint16_t* xhB   = (uint16_t*)alloc((size_t)256 * 1024 * 2);
  uint16_t* xhC   = (uint16_t*)alloc((size_t)16 * 1024 * 2);
  float*    Fpart = (float*)alloc((size_t)4096 * 512 * 4);
  float*    Gf    = (float*)alloc((size_t)16 * 1536 * 4);
  float*    Fc    = (float*)alloc((size_t)16 * 512 * 4);
  float*    CupA  = (float*)alloc((size_t)16 * 512 * 4);

  // ---- merged convert: all x + 4 weight matrices ----
  {
    long n4x = NTOT * 512 / 4;
    k_conv_all<<<8192, 256, 0, stream>>>(
        (const float4*)x, (ushort4*)Xbf, n4x,
        (const float4*)wi_w, (const float4*)wo_w,
        (const float4*)wu_w, (const float4*)wf_w, (ushort4*)Wgw);
  }

  // ---- leaf level + FxAll gemm in ONE launch (4096 + 140 blocks) ----
  k_leaf_fx<<<4236, 256, 0, stream>>>(
      Xbf + offs[4] * 512, Wg, wi_b, wo_b, wu_b,
      Cbf, Xbf + offs[3] * 512, xhA,
      Xbf, Wf, FxAll);
  k_fc_combine<4><<<2048, 256, 0, stream>>>(Cbf, Wf + 512, 1024,
                                            FxAll + offs[3] * 512, wf_b, Fpart);

  // ---- level 3 (M=4096, K=1024): MF=2 (BM=64), nTm=64 -> 512 blocks ----
  k_level<true, 2><<<512, 256, 0, stream>>>(
      xhA, 1024, 1024, Wg, wi_b, wo_b, wu_b, Fpart,
      CbfU, Xbf + offs[2] * 512, xhB);
  k_fc_combine<2><<<256, 256, 0, stream>>>(CbfU, Wf + 512, 1024,
                                           FxAll + offs[2] * 512, wf_b, Fpart);

  // ---- level 2 (M=256, K=1024): MF=2, nTm=4 -> 32 blocks (plain map) ----
  k_level<true, 2><<<32, 256, 0, stream>>>(
      xhB, 1024, 1024, Wg, wi_b, wo_b, wu_b, Fpart,
      CbfU2, Xbf + offs[1] * 512, xhC);

  // ---- lvl2 fc + lvl1 gate dots in ONE launch (16 + 6144 blocks) ----
  k_fcdot<<<6160, 256, 0, stream>>>(CbfU2, Wf + 512,
                                    FxAll + offs[1] * 512, wf_b, Fpart,
                                    xhC, Wg, Gf);

  // ---- level 1 tail (final + hsum + root pack) ----
  k_lvl1_tail<<<1, 1024, 0, stream>>>(Gf, Fpart, wi_b, wo_b, wu_b,
                                      CupA, Xbf + offs[0] * 512, xhC);

  // ---- level 0 (root): merged gate-dot + Fc-dot, then fused tail ----
  {
    long waves = 1536 + 16L * 512;       // 9728 waves = 2432 blocks exactly
    k_dot_merge<<<(int)(waves / 4), 256, 0, stream>>>(
        xhC, Wg, Gf, CupA, wf_w + 512, Fc);
  }
  k_root_tail<<<1, 128, 0, stream>>>(Fc, FxAll, wf_b, CupA, Gf,
                                     wi_b, wo_b, wu_b,
                                     (float*)d_out, (float*)d_out + 512);
}

// Round 9
// 464.775 us; speedup vs baseline: 1.3338x; 1.0150x over previous
//
#include <hip/hip_runtime.h>
#include <stdint.h>
#include <stddef.h>

// ---------------------------------------------------------------------------
// CSTreeLSTM on gfx950. Levels 1,16,256,4096,65536 (x offsets 0,1,17,273,4369).
// Round 17: mid-level gate-GEMMs overlapped with the preceding fc pass.
// k_level split: gates-GEMM (writes raw pre-acts G3, independent of Fpart)
// + k_level_final (elementwise gates+Fpart -> Cbf/H + per-parent h-sum/xh).
//  - k_fc4_l3g: leaf fc (2048 blks) || lvl3 gates (512 blks), one launch.
//  - k_fc2_l2g: lvl3 fc (256 blks) || lvl2 gates (32 blks), one launch.
// Core GEMM bodies byte-identical to r16 (2-phase, T2 swizzle, conflicts=0,
// 3 blocks/CU). Leaf pair (k_leaf_fx + its fc inside k_fc4_l3g) unchanged.
// ---------------------------------------------------------------------------

typedef __bf16 bf16x8 __attribute__((ext_vector_type(8)));
typedef float  f32x4  __attribute__((ext_vector_type(4)));
typedef void __attribute__((address_space(3))) lds_void_t;
typedef void __attribute__((address_space(1))) gbl_void_t;

__device__ __forceinline__ uint16_t f2bf(float f) {
  union { __bf16 b; uint16_t u; } v;
  v.b = (__bf16)f;              // RTNE, compiler emits v_cvt_pk_bf16_f32
  return v.u;
}
__device__ __forceinline__ float bf2f(uint16_t u) {
  union { uint32_t u; float f; } v; v.u = (uint32_t)u << 16;
  return v.f;
}
// native v_rcp_f32 (~1 ulp) -- error budget is huge
__device__ __forceinline__ float sig_(float x) {
  return __builtin_amdgcn_rcpf(1.0f + __expf(-x));
}
// tanh(x) = 2/(1+exp(-2x)) - 1 : mul+exp+add+rcp+fma, no clamp, inf-safe
__device__ __forceinline__ float tanh_(float x) {
  return __builtin_fmaf(2.f,
      __builtin_amdgcn_rcpf(1.f + __expf(-2.f * x)), -1.f);
}

// ---- merged convert: all x rows + 4 weight matrices ------------------------
__global__ void k_conv_all(const float4* __restrict__ x,
                           ushort4* __restrict__ xdst, long n4x,
                           const float4* __restrict__ w0,
                           const float4* __restrict__ w1,
                           const float4* __restrict__ w2,
                           const float4* __restrict__ w3,
                           ushort4* __restrict__ wdst) {
  const long per4 = (long)512 * 1024 / 4;
  const long total = n4x + 4 * per4;
  long i = blockIdx.x * (long)blockDim.x + threadIdx.x;
  long stride = (long)gridDim.x * blockDim.x;
  for (; i < total; i += stride) {
    float4 v;
    ushort4* d;
    if (i < n4x) {
      v = x[i];
      d = xdst + i;
    } else {
      long j = i - n4x;
      long seg = j / per4, off2 = j - seg * per4;
      const float4* s = (seg == 0) ? w0 : (seg == 1) ? w1
                       : (seg == 2) ? w2 : w3;
      v = s[off2];
      d = wdst + j;
    }
    ushort4 r;
    r.x = f2bf(v.x); r.y = f2bf(v.y); r.z = f2bf(v.z); r.w = f2bf(v.w);
    *d = r;
  }
}

#define BM 128
#define BN 128
#define BK 32

// ---- merged leaf k_level + FxAll gemm_bt (round-16 verbatim) ---------------
__global__ __launch_bounds__(256, 3)
void k_leaf_fx(const uint16_t* __restrict__ Xleaf,       // Xbf + offs4*512
               const uint16_t* __restrict__ Wg,
               const float* __restrict__ bi, const float* __restrict__ bo,
               const float* __restrict__ bu,
               uint16_t* __restrict__ Cbf,
               const uint16_t* __restrict__ Xnext,       // Xbf + offs3*512
               uint16_t* __restrict__ xh_next,           // xhA
               const uint16_t* __restrict__ Xbf,         // for FxAll A
               const uint16_t* __restrict__ Wf,          // FxAll B
               float* __restrict__ FxAll) {
  __shared__ uint16_t smem[20480];                       // 40 KB pool
  const int tid = threadIdx.x, lane = tid & 63, wave = tid >> 6;
  const int lrow = lane & 15, quad = lane >> 4;

  if (blockIdx.x < 4096) {
    uint16_t* As = smem;                 // 128*64
    uint16_t* Bs = smem + 8192;          // 192*64
    const int wm = (wave >> 1) * 64, wn = (wave & 1) * 32;
    long tm, tn;
    {
      int b = blockIdx.x;
      int x = b & 7, j = b >> 3, per = 64;       // nTm=512
      tn = j & 7; tm = (long)x * per + (j >> 3);
    }
    f32x4 acc[3][4][2] = {};
    const int srow = lane >> 3;
    const int scol = (((lane & 7) ^ srow) << 3);
    const int rsw = lrow & 7;
    const int pc[2] = { ((0 + quad) ^ rsw) << 3, ((4 + quad) ^ rsw) << 3 };

    for (int k0 = 0; k0 < 512; k0 += 64) {
#pragma unroll
      for (int j = 0; j < 4; ++j) {
        int grp = wave * 4 + j;
        int row = grp * 8 + srow;
        const uint16_t* gp = Xleaf + (tm * 128 + row) * 512L + k0 + scol;
        __builtin_amdgcn_global_load_lds((gbl_void_t*)(uintptr_t)gp,
            (lds_void_t*)&As[grp * 512], 16, 0, 0);
      }
#pragma unroll
      for (int j = 0; j < 6; ++j) {
        int cc = wave * 6 + j;
        int g  = cc >> 3;
        long grow = (long)g * 512 + tn * 64 + (cc & 7) * 8 + srow;
        const uint16_t* gp = Wg + grow * 1024 + k0 + scol;
        __builtin_amdgcn_global_load_lds((gbl_void_t*)(uintptr_t)gp,
            (lds_void_t*)&Bs[cc * 512], 16, 0, 0);
      }
      __syncthreads();
#pragma unroll
      for (int h = 0; h < 2; ++h) {
        bf16x8 a[4];
#pragma unroll
        for (int f = 0; f < 4; ++f)
          a[f] = *(const bf16x8*)&As[(wm + f * 16 + lrow) * 64 + pc[h]];
#pragma unroll
        for (int g = 0; g < 3; ++g) {
          bf16x8 b0 = *(const bf16x8*)&Bs[(g * 64 + wn + lrow) * 64 + pc[h]];
          bf16x8 b1 = *(const bf16x8*)&Bs[(g * 64 + wn + 16 + lrow) * 64 +
                                          pc[h]];
#pragma unroll
          for (int fm = 0; fm < 4; ++fm) {
            acc[g][fm][0] = __builtin_amdgcn_mfma_f32_16x16x32_bf16(
                a[fm], b0, acc[g][fm][0], 0, 0, 0);
            acc[g][fm][1] = __builtin_amdgcn_mfma_f32_16x16x32_bf16(
                a[fm], b1, acc[g][fm][1], 0, 0, 0);
          }
        }
      }
      __syncthreads();
    }
#pragma unroll
    for (int fn = 0; fn < 2; ++fn) {
      long col = tn * 64 + wn + fn * 16 + lrow;
      float biv = bi[col], bov = bo[col], buv = bu[col];
#pragma unroll
      for (int fm = 0; fm < 4; ++fm) {
        long row0 = tm * 128 + wm + fm * 16 + quad * 4;
        long pg   = tm * 8 + (wm >> 4) + fm;
        float hs = 0.f;
#pragma unroll
        for (int r = 0; r < 4; ++r) {
          long row = row0 + r;
          float iv = sig_(acc[0][fm][fn][r] + biv);
          float ov = sig_(acc[1][fm][fn][r] + bov);
          float uv = tanh_(acc[2][fm][fn][r] + buv);
          float c  = iv * uv;
          Cbf[row * 512 + col] = f2bf(c);
          hs += ov * tanh_(c);
        }
        hs += __shfl_xor(hs, 16, 64);
        hs += __shfl_xor(hs, 32, 64);
        if (quad == 0) {
          xh_next[pg * 1024 + col]       = Xnext[pg * 512 + col];
          xh_next[pg * 1024 + 512 + col] = f2bf(hs);
        }
      }
    }
  } else {
    uint16_t* As = smem;                 // 128*32
    uint16_t* Bs = smem + 4096;          // 128*32
    const int wm = (wave >> 1) * 64, wn = (wave & 1) * 64;
    int bid2 = (int)blockIdx.x - 4096;
    const long tm = bid2 % 35, tn = bid2 / 35;
    f32x4 acc[4][4] = {};
    const int srow2 = lane >> 2, scol2 = (lane & 3) * 8;
    for (int k0 = 0; k0 < 512; k0 += BK) {
#pragma unroll
      for (int i = 0; i < 2; ++i) {
        int row = i * 64 + wave * 16 + srow2;
        const uint16_t* gp = Xbf + (tm * BM + row) * 512L + k0 + scol2;
        __builtin_amdgcn_global_load_lds((gbl_void_t*)(uintptr_t)gp,
            (lds_void_t*)&As[i * 2048 + wave * 512], 16, 0, 0);
      }
#pragma unroll
      for (int i = 0; i < 2; ++i) {
        int row = i * 64 + wave * 16 + srow2;
        const uint16_t* gp = Wf + (tn * BN + row) * 1024L + k0 + scol2;
        __builtin_amdgcn_global_load_lds((gbl_void_t*)(uintptr_t)gp,
            (lds_void_t*)&Bs[i * 2048 + wave * 512], 16, 0, 0);
      }
      __syncthreads();
      bf16x8 a[4], b[4];
#pragma unroll
      for (int f = 0; f < 4; ++f)
        a[f] = *(const bf16x8*)&As[(wm + f * 16 + lrow) * BK + quad * 8];
#pragma unroll
      for (int f = 0; f < 4; ++f)
        b[f] = *(const bf16x8*)&Bs[(wn + f * 16 + lrow) * BK + quad * 8];
#pragma unroll
      for (int fm = 0; fm < 4; ++fm)
#pragma unroll
        for (int fn = 0; fn < 4; ++fn)
          acc[fm][fn] = __builtin_amdgcn_mfma_f32_16x16x32_bf16(
              a[fm], b[fn], acc[fm][fn], 0, 0, 0);
      __syncthreads();
    }
#pragma unroll
    for (int fm = 0; fm < 4; ++fm)
#pragma unroll
      for (int fn = 0; fn < 4; ++fn) {
        long col  = tn * BN + wn + fn * 16 + lrow;
        long row0 = tm * BM + wm + fm * 16 + quad * 4;
#pragma unroll
        for (int r = 0; r < 4; ++r)
          FxAll[(row0 + r) * 512 + col] = acc[fm][fn][r];
      }
  }
}

// ---- merged: leaf fc_combine (2048 blks) || lvl3 gates GEMM (512 blks) -----
// fc branch: M=65536 BMT=128 nTm=512 (XCD swizzle). Gates branch: M=4096,
// MF=2 (BMT=64), K=1024, nTm=64 (XCD swizzle); writes raw pre-acts to G3.
__global__ __launch_bounds__(256, 3)
void k_fc4_l3g(const uint16_t* __restrict__ Cbf,         // leaf C (fc A)
               const uint16_t* __restrict__ Wfc,         // Wf+512, ldb 1024
               const float* __restrict__ Fx,             // FxAll+offs3*512
               const float* __restrict__ bfb,
               float* __restrict__ Fpart,
               const uint16_t* __restrict__ xhA,         // lvl3 A, lda 1024
               const uint16_t* __restrict__ Wg,
               float* __restrict__ G3) {
  __shared__ uint16_t smem[16384];                       // 32 KB pool
  const int tid = threadIdx.x, lane = tid & 63, wave = tid >> 6;
  const int lrow = lane & 15, quad = lane >> 4;
  const int srow = lane >> 3;
  const int scol = (((lane & 7) ^ srow) << 3);
  const int rsw = lrow & 7;
  const int pc[2] = { ((0 + quad) ^ rsw) << 3, ((4 + quad) ^ rsw) << 3 };

  if (blockIdx.x < 2048) {
    // ----- fc4 (r16 k_fc_combine<4> body, nTm=512 hardcoded) -----
    uint16_t* As = smem;                 // 128*64 = 16 KB
    uint16_t* Bs = smem + 8192;          // 128*64 = 16 KB
    const int wm = (wave >> 1) * 64, wn = (wave & 1) * 64;
    long tm, tn;
    {
      int b = blockIdx.x;
      int x = b & 7, j = b >> 3, per = 64;       // nTm=512
      tn = j & 3; tm = (long)x * per + (j >> 2);
    }
    f32x4 acc[4][4] = {};
    for (int k0 = 0; k0 < 512; k0 += 64) {
#pragma unroll
      for (int j = 0; j < 4; ++j) {
        int grp = wave * 4 + j;
        int row = grp * 8 + srow;
        const uint16_t* gp = Cbf + (tm * 128 + row) * 512L + k0 + scol;
        __builtin_amdgcn_global_load_lds((gbl_void_t*)(uintptr_t)gp,
            (lds_void_t*)&As[grp * 512], 16, 0, 0);
      }
#pragma unroll
      for (int j = 0; j < 4; ++j) {
        int row = wave * 32 + j * 8 + srow;
        const uint16_t* gp = Wfc + (tn * BN + row) * 1024L + k0 + scol;
        __builtin_amdgcn_global_load_lds((gbl_void_t*)(uintptr_t)gp,
            (lds_void_t*)&Bs[(wave * 32 + j * 8) * 64], 16, 0, 0);
      }
      __syncthreads();
#pragma unroll
      for (int h = 0; h < 2; ++h) {
        bf16x8 a[4], b[4];
#pragma unroll
        for (int f = 0; f < 4; ++f)
          a[f] = *(const bf16x8*)&As[(wm + f * 16 + lrow) * 64 + pc[h]];
#pragma unroll
        for (int f = 0; f < 4; ++f)
          b[f] = *(const bf16x8*)&Bs[(wn + f * 16 + lrow) * 64 + pc[h]];
#pragma unroll
        for (int fm = 0; fm < 4; ++fm)
#pragma unroll
          for (int fn = 0; fn < 4; ++fn)
            acc[fm][fn] = __builtin_amdgcn_mfma_f32_16x16x32_bf16(
                a[fm], b[fn], acc[fm][fn], 0, 0, 0);
      }
      __syncthreads();
    }
#pragma unroll
    for (int fm = 0; fm < 4; ++fm) {
      long pg   = tm * 8 + (wm >> 4) + fm;
      long row0 = tm * 128 + wm + fm * 16 + quad * 4;
#pragma unroll
      for (int fn = 0; fn < 4; ++fn) {
        long col = tn * BN + wn + fn * 16 + lrow;
        float fx = Fx[pg * 512 + col] + bfb[col];
        float t = 0.f;
#pragma unroll
        for (int r = 0; r < 4; ++r)
          t += sig_(fx + acc[fm][fn][r]) * bf2f(Cbf[(row0 + r) * 512 + col]);
        t += __shfl_xor(t, 16, 64);
        t += __shfl_xor(t, 32, 64);
        if (quad == 0) Fpart[pg * 512 + col] = t;
      }
    }
  } else {
    // ----- lvl3 gates (r16 k_level<*,2> GEMM body; epilogue -> G3) -----
    uint16_t* As = smem;                 // 64*64 = 8 KB
    uint16_t* Bs = smem + 4096;          // 192*64 = 24 KB
    const int wm = (wave >> 1) * 32, wn = (wave & 1) * 32;
    long tm, tn;
    {
      int b = (int)blockIdx.x - 2048;
      int x = b & 7, j = b >> 3, per = 8;        // nTm=64
      tn = j & 7; tm = (long)x * per + (j >> 3);
    }
    f32x4 acc[3][2][2] = {};
    for (int k0 = 0; k0 < 1024; k0 += 64) {
#pragma unroll
      for (int j = 0; j < 2; ++j) {
        int grp = wave * 2 + j;
        int row = grp * 8 + srow;
        const uint16_t* gp = xhA + (tm * 64 + row) * 1024L + k0 + scol;
        __builtin_amdgcn_global_load_lds((gbl_void_t*)(uintptr_t)gp,
            (lds_void_t*)&As[grp * 512], 16, 0, 0);
      }
#pragma unroll
      for (int j = 0; j < 6; ++j) {
        int cc = wave * 6 + j;
        int g  = cc >> 3;
        long grow = (long)g * 512 + tn * 64 + (cc & 7) * 8 + srow;
        const uint16_t* gp = Wg + grow * 1024 + k0 + scol;
        __builtin_amdgcn_global_load_lds((gbl_void_t*)(uintptr_t)gp,
            (lds_void_t*)&Bs[cc * 512], 16, 0, 0);
      }
      __syncthreads();
#pragma unroll
      for (int h = 0; h < 2; ++h) {
        bf16x8 a[2];
#pragma unroll
        for (int f = 0; f < 2; ++f)
          a[f] = *(const bf16x8*)&As[(wm + f * 16 + lrow) * 64 + pc[h]];
#pragma unroll
        for (int g = 0; g < 3; ++g) {
          bf16x8 b0 = *(const bf16x8*)&Bs[(g * 64 + wn + lrow) * 64 + pc[h]];
          bf16x8 b1 = *(const bf16x8*)&Bs[(g * 64 + wn + 16 + lrow) * 64 +
                                          pc[h]];
#pragma unroll
          for (int fm = 0; fm < 2; ++fm) {
            acc[g][fm][0] = __builtin_amdgcn_mfma_f32_16x16x32_bf16(
                a[fm], b0, acc[g][fm][0], 0, 0, 0);
            acc[g][fm][1] = __builtin_amdgcn_mfma_f32_16x16x32_bf16(
                a[fm], b1, acc[g][fm][1], 0, 0, 0);
          }
        }
      }
      __syncthreads();
    }
#pragma unroll
    for (int fn = 0; fn < 2; ++fn) {
      long col = tn * 64 + wn + fn * 16 + lrow;
#pragma unroll
      for (int fm = 0; fm < 2; ++fm) {
        long row0 = tm * 64 + wm + fm * 16 + quad * 4;
#pragma unroll
        for (int r = 0; r < 4; ++r) {
          long row = row0 + r;
#pragma unroll
          for (int g = 0; g < 3; ++g)
            G3[row * 1536 + g * 512 + col] = acc[g][fm][fn][r];
        }
      }
    }
  }
}

// ---- level final: gates(G3)+Fpart -> Cbf/H; per-parent h-sum + xh pack -----
// One block per parent (16 children), 128 threads (4 cols each).
__global__ void k_level_final(const float* __restrict__ G3,
                              const float* __restrict__ Fpart,
                              const float* __restrict__ bi,
                              const float* __restrict__ bo,
                              const float* __restrict__ bu,
                              uint16_t* __restrict__ Cbf_out,
                              const uint16_t* __restrict__ Xnext,
                              uint16_t* __restrict__ xh_next) {
  const long p = blockIdx.x;
  const int hq = (threadIdx.x & 127) << 2;
  float4 b_i = *(const float4*)(bi + hq);
  float4 b_o = *(const float4*)(bo + hq);
  float4 b_u = *(const float4*)(bu + hq);
  const float* bip = &b_i.x; const float* bop = &b_o.x;
  const float* bup = &b_u.x;
  float hs[4] = {0.f, 0.f, 0.f, 0.f};
#pragma unroll 4
  for (int k = 0; k < 16; ++k) {
    long row = p * 16 + k;
    float4 gi = *(const float4*)(G3 + row * 1536 + hq);
    float4 go = *(const float4*)(G3 + row * 1536 + 512 + hq);
    float4 gu = *(const float4*)(G3 + row * 1536 + 1024 + hq);
    float4 fp = *(const float4*)(Fpart + row * 512 + hq);
    const float* gip = &gi.x; const float* gop = &go.x;
    const float* gup = &gu.x; const float* fpp = &fp.x;
    ushort4 cw; unsigned short* cwp = &cw.x;
#pragma unroll
    for (int j = 0; j < 4; ++j) {
      float iv = sig_(gip[j] + bip[j]);
      float ov = sig_(gop[j] + bop[j]);
      float uv = tanh_(gup[j] + bup[j]);
      float c  = iv * uv + fpp[j];
      cwp[j] = f2bf(c);
      hs[j] += ov * tanh_(c);
    }
    *(ushort4*)(Cbf_out + row * 512 + hq) = cw;
  }
  *(ushort4*)(xh_next + p * 1024 + hq) = *(const ushort4*)(Xnext + p * 512 + hq);
  ushort4 hw = {f2bf(hs[0]), f2bf(hs[1]), f2bf(hs[2]), f2bf(hs[3])};
  *(ushort4*)(xh_next + p * 1024 + 512 + hq) = hw;
}

// ---- merged: lvl3 fc_combine (256 blks) || lvl2 gates GEMM (32 blks) -------
__global__ __launch_bounds__(256, 3)
void k_fc2_l2g(const uint16_t* __restrict__ CbfU,        // lvl3 C (fc A)
               const uint16_t* __restrict__ Wfc,         // Wf+512, ldb 1024
               const float* __restrict__ Fx,             // FxAll+offs2*512
               const float* __restrict__ bfb,
               float* __restrict__ Fpart,
               const uint16_t* __restrict__ xhB,         // lvl2 A, lda 1024
               const uint16_t* __restrict__ Wg,
               float* __restrict__ G3) {
  __shared__ uint16_t smem[16384];                       // 32 KB pool
  const int tid = threadIdx.x, lane = tid & 63, wave = tid >> 6;
  const int lrow = lane & 15, quad = lane >> 4;
  const int srow = lane >> 3;
  const int scol = (((lane & 7) ^ srow) << 3);
  const int rsw = lrow & 7;
  const int pc[2] = { ((0 + quad) ^ rsw) << 3, ((4 + quad) ^ rsw) << 3 };

  if (blockIdx.x < 256) {
    // ----- fc2 (r16 k_fc_combine<2> body, nTm=64 hardcoded) -----
    uint16_t* As = smem;                 // 64*64 = 8 KB
    uint16_t* Bs = smem + 4096;          // 128*64 = 16 KB
    const int wm = (wave >> 1) * 32, wn = (wave & 1) * 64;
    long tm, tn;
    {
      int b = blockIdx.x;
      int x = b & 7, j = b >> 3, per = 8;        // nTm=64
      tn = j & 3; tm = (long)x * per + (j >> 2);
    }
    f32x4 acc[2][4] = {};
    for (int k0 = 0; k0 < 512; k0 += 64) {
#pragma unroll
      for (int j = 0; j < 2; ++j) {
        int grp = wave * 2 + j;
        int row = grp * 8 + srow;
        const uint16_t* gp = CbfU + (tm * 64 + row) * 512L + k0 + scol;
        __builtin_amdgcn_global_load_lds((gbl_void_t*)(uintptr_t)gp,
            (lds_void_t*)&As[grp * 512], 16, 0, 0);
      }
#pragma unroll
      for (int j = 0; j < 4; ++j) {
        int row = wave * 32 + j * 8 + srow;
        const uint16_t* gp = Wfc + (tn * BN + row) * 1024L + k0 + scol;
        __builtin_amdgcn_global_load_lds((gbl_void_t*)(uintptr_t)gp,
            (lds_void_t*)&Bs[(wave * 32 + j * 8) * 64], 16, 0, 0);
      }
      __syncthreads();
#pragma unroll
      for (int h = 0; h < 2; ++h) {
        bf16x8 a[2], b[4];
#pragma unroll
        for (int f = 0; f < 2; ++f)
          a[f] = *(const bf16x8*)&As[(wm + f * 16 + lrow) * 64 + pc[h]];
#pragma unroll
        for (int f = 0; f < 4; ++f)
          b[f] = *(const bf16x8*)&Bs[(wn + f * 16 + lrow) * 64 + pc[h]];
#pragma unroll
        for (int fm = 0; fm < 2; ++fm)
#pragma unroll
          for (int fn = 0; fn < 4; ++fn)
            acc[fm][fn] = __builtin_amdgcn_mfma_f32_16x16x32_bf16(
                a[fm], b[fn], acc[fm][fn], 0, 0, 0);
      }
      __syncthreads();
    }
#pragma unroll
    for (int fm = 0; fm < 2; ++fm) {
      long pg   = tm * 4 + (wm >> 4) + fm;
      long row0 = tm * 64 + wm + fm * 16 + quad * 4;
#pragma unroll
      for (int fn = 0; fn < 4; ++fn) {
        long col = tn * BN + wn + fn * 16 + lrow;
        float fx = Fx[pg * 512 + col] + bfb[col];
        float t = 0.f;
#pragma unroll
        for (int r = 0; r < 4; ++r)
          t += sig_(fx + acc[fm][fn][r]) * bf2f(CbfU[(row0 + r) * 512 + col]);
        t += __shfl_xor(t, 16, 64);
        t += __shfl_xor(t, 32, 64);
        if (quad == 0) Fpart[pg * 512 + col] = t;
      }
    }
  } else {
    // ----- lvl2 gates (MF=2, nTm=4 plain map; epilogue -> G3) -----
    uint16_t* As = smem;                 // 64*64 = 8 KB
    uint16_t* Bs = smem + 4096;          // 192*64 = 24 KB
    const int wm = (wave >> 1) * 32, wn = (wave & 1) * 32;
    int b = (int)blockIdx.x - 256;
    long tm = b >> 3, tn = b & 7;
    f32x4 acc[3][2][2] = {};
    for (int k0 = 0; k0 < 1024; k0 += 64) {
#pragma unroll
      for (int j = 0; j < 2; ++j) {
        int grp = wave * 2 + j;
        int row = grp * 8 + srow;
        const uint16_t* gp = xhB + (tm * 64 + row) * 1024L + k0 + scol;
        __builtin_amdgcn_global_load_lds((gbl_void_t*)(uintptr_t)gp,
            (lds_void_t*)&As[grp * 512], 16, 0, 0);
      }
#pragma unroll
      for (int j = 0; j < 6; ++j) {
        int cc = wave * 6 + j;
        int g  = cc >> 3;
        long grow = (long)g * 512 + tn * 64 + (cc & 7) * 8 + srow;
        const uint16_t* gp = Wg + grow * 1024 + k0 + scol;
        __builtin_amdgcn_global_load_lds((gbl_void_t*)(uintptr_t)gp,
            (lds_void_t*)&Bs[cc * 512], 16, 0, 0);
      }
      __syncthreads();
#pragma unroll
      for (int h = 0; h < 2; ++h) {
        bf16x8 a[2];
#pragma unroll
        for (int f = 0; f < 2; ++f)
          a[f] = *(const bf16x8*)&As[(wm + f * 16 + lrow) * 64 + pc[h]];
#pragma unroll
        for (int g = 0; g < 3; ++g) {
          bf16x8 b0 = *(const bf16x8*)&Bs[(g * 64 + wn + lrow) * 64 + pc[h]];
          bf16x8 b1 = *(const bf16x8*)&Bs[(g * 64 + wn + 16 + lrow) * 64 +
                                          pc[h]];
#pragma unroll
          for (int fm = 0; fm < 2; ++fm) {
            acc[g][fm][0] = __builtin_amdgcn_mfma_f32_16x16x32_bf16(
                a[fm], b0, acc[g][fm][0], 0, 0, 0);
            acc[g][fm][1] = __builtin_amdgcn_mfma_f32_16x16x32_bf16(
                a[fm], b1, acc[g][fm][1], 0, 0, 0);
          }
        }
      }
      __syncthreads();
    }
#pragma unroll
    for (int fn = 0; fn < 2; ++fn) {
      long col = tn * 64 + wn + fn * 16 + lrow;
#pragma unroll
      for (int fm = 0; fm < 2; ++fm) {
        long row0 = tm * 64 + wm + fm * 16 + quad * 4;
#pragma unroll
        for (int r = 0; r < 4; ++r) {
          long row = row0 + r;
#pragma unroll
          for (int g = 0; g < 3; ++g)
            G3[row * 1536 + g * 512 + col] = acc[g][fm][fn][r];
        }
      }
    }
  }
}

// ---- merged lvl2 fc_combine (16 blocks) + lvl1 gate dots (r16 verbatim) ----
__global__ __launch_bounds__(256)
void k_fcdot(const uint16_t* __restrict__ Cbf,           // CbfU2
             const uint16_t* __restrict__ Wfc,           // Wf + 512
             const float* __restrict__ Fx,
             const float* __restrict__ bfb,
             float* __restrict__ Fpart,
             const uint16_t* __restrict__ xhC,
             const uint16_t* __restrict__ Wg,
             float* __restrict__ Gf) {
  __shared__ uint16_t smem[12288];                       // 24 KB (fc branch)
  const int tid = threadIdx.x, lane = tid & 63, wave = tid >> 6;
  if (blockIdx.x < 16) {
    uint16_t* As = smem;                 // 64*64
    uint16_t* Bs = smem + 4096;          // 128*64
    const int lrow = lane & 15, quad = lane >> 4;
    const int wm = (wave >> 1) * 32, wn = (wave & 1) * 64;
    int b = blockIdx.x;
    long tm = b >> 2, tn = b & 3;        // nTm=4 plain map
    f32x4 acc[2][4] = {};
    const int srow = lane >> 3;
    const int scol = (((lane & 7) ^ srow) << 3);
    const int rsw = lrow & 7;
    const int pc[2] = { ((0 + quad) ^ rsw) << 3, ((4 + quad) ^ rsw) << 3 };
    for (int k0 = 0; k0 < 512; k0 += 64) {
#pragma unroll
      for (int j = 0; j < 2; ++j) {
        int grp = wave * 2 + j;
        int row = grp * 8 + srow;
        const uint16_t* gp = Cbf + (tm * 64 + row) * 512L + k0 + scol;
        __builtin_amdgcn_global_load_lds((gbl_void_t*)(uintptr_t)gp,
            (lds_void_t*)&As[grp * 512], 16, 0, 0);
      }
#pragma unroll
      for (int j = 0; j < 4; ++j) {
        int row = wave * 32 + j * 8 + srow;
        const uint16_t* gp = Wfc + (tn * 128 + row) * 1024L + k0 + scol;
        __builtin_amdgcn_global_load_lds((gbl_void_t*)(uintptr_t)gp,
            (lds_void_t*)&Bs[(wave * 32 + j * 8) * 64], 16, 0, 0);
      }
      __syncthreads();
#pragma unroll
      for (int h = 0; h < 2; ++h) {
        bf16x8 a[2], bb[4];
#pragma unroll
        for (int f = 0; f < 2; ++f)
          a[f] = *(const bf16x8*)&As[(wm + f * 16 + lrow) * 64 + pc[h]];
#pragma unroll
        for (int f = 0; f < 4; ++f)
          bb[f] = *(const bf16x8*)&Bs[(wn + f * 16 + lrow) * 64 + pc[h]];
#pragma unroll
        for (int fm = 0; fm < 2; ++fm)
#pragma unroll
          for (int fn = 0; fn < 4; ++fn)
            acc[fm][fn] = __builtin_amdgcn_mfma_f32_16x16x32_bf16(
                a[fm], bb[fn], acc[fm][fn], 0, 0, 0);
      }
      __syncthreads();
    }
#pragma unroll
    for (int fm = 0; fm < 2; ++fm) {
      long pg   = tm * 4 + (wm >> 4) + fm;
      long row0 = tm * 64 + wm + fm * 16 + quad * 4;
#pragma unroll
      for (int fn = 0; fn < 4; ++fn) {
        long col = tn * 128 + wn + fn * 16 + lrow;
        float fx = Fx[pg * 512 + col] + bfb[col];
        float t = 0.f;
#pragma unroll
        for (int r = 0; r < 4; ++r)
          t += sig_(fx + acc[fm][fn][r]) * bf2f(Cbf[(row0 + r) * 512 + col]);
        t += __shfl_xor(t, 16, 64);
        t += __shfl_xor(t, 32, 64);
        if (quad == 0) Fpart[pg * 512 + col] = t;
      }
    }
  } else {
    int wid = (int)(((long)(blockIdx.x - 16) * 256 + tid) >> 6);
    if (wid >= 16 * 1536) return;
    int m = wid / 1536, n = wid - m * 1536;
    const uint16_t* a = xhC + (long)m * 1024;
    const uint16_t* b = Wg + (long)n * 1024;
    int k0 = lane * 16;
    float s = 0.f;
#pragma unroll
    for (int j = 0; j < 16; j += 4) {
      ushort4 av = *(const ushort4*)(a + k0 + j);
      ushort4 bv = *(const ushort4*)(b + k0 + j);
      s += bf2f(av.x) * bf2f(bv.x) + bf2f(av.y) * bf2f(bv.y)
         + bf2f(av.z) * bf2f(bv.z) + bf2f(av.w) * bf2f(bv.w);
    }
#pragma unroll
    for (int off = 32; off; off >>= 1) s += __shfl_xor(s, off, 64);
    if (lane == 0) Gf[(long)m * 1536 + n] = s;
  }
}

// ---- merged root dots: gates (bf16) + Fc (f32) (r16 verbatim) --------------
__global__ void k_dot_merge(const uint16_t* __restrict__ xhC,
                            const uint16_t* __restrict__ Wg,
                            float* __restrict__ Gf,
                            const float* __restrict__ CupA,
                            const float* __restrict__ WfF,
                            float* __restrict__ Fc) {
  int wid  = (int)((blockIdx.x * (long)blockDim.x + threadIdx.x) >> 6);
  int lane = threadIdx.x & 63;
  if (wid < 1536) {
    const uint16_t* a = xhC;
    const uint16_t* b = Wg + (long)wid * 1024;
    int k0 = lane * 16;
    float s = 0.f;
#pragma unroll
    for (int j = 0; j < 16; j += 4) {
      ushort4 av = *(const ushort4*)(a + k0 + j);
      ushort4 bv = *(const ushort4*)(b + k0 + j);
      s += bf2f(av.x) * bf2f(bv.x) + bf2f(av.y) * bf2f(bv.y)
         + bf2f(av.z) * bf2f(bv.z) + bf2f(av.w) * bf2f(bv.w);
    }
#pragma unroll
    for (int off = 32; off; off >>= 1) s += __shfl_xor(s, off, 64);
    if (lane == 0) Gf[wid] = s;
  } else {
    int w2 = wid - 1536;
    if (w2 >= 16 * 512) return;
    int m = w2 >> 9, n = w2 & 511;
    const float* a = CupA + (long)m * 512;
    const float* b = WfF + (long)n * 1024;
    int k0 = lane * 8;
    float s = 0.f;
#pragma unroll
    for (int j = 0; j < 8; j += 4) {
      float4 av = *(const float4*)(a + k0 + j);
      float4 bv = *(const float4*)(b + k0 + j);
      s += av.x * bv.x + av.y * bv.y + av.z * bv.z + av.w * bv.w;
    }
#pragma unroll
    for (int off = 32; off; off >>= 1) s += __shfl_xor(s, off, 64);
    if (lane == 0) Fc[(long)m * 512 + n] = s;
  }
}

// ---- level-1 tail (r16 verbatim) -------------------------------------------
__global__ __launch_bounds__(1024)
void k_lvl1_tail(const float* __restrict__ G,
                 const float* __restrict__ Fpart,
                 const float* __restrict__ bi,
                 const float* __restrict__ bo,
                 const float* __restrict__ bu,
                 float* __restrict__ Cv,               // CupA (16x512)
                 const uint16_t* __restrict__ xroot,   // Xbf row 0
                 uint16_t* __restrict__ xh) {          // xhC row 0 pack
  __shared__ float Hl[16 * 512];                       // 32 KB
  const int tid = threadIdx.x;
#pragma unroll
  for (int it = 0; it < 2; ++it) {
    int idx = it * 1024 + tid;
    int p = idx >> 7, hq = (idx & 127) << 2;
    const float* g = G + (long)p * 1536;
    float4 gi = *(const float4*)(g + hq);
    float4 go = *(const float4*)(g + 512 + hq);
    float4 gu = *(const float4*)(g + 1024 + hq);
    float4 b_i = *(const float4*)(bi + hq);
    float4 b_o = *(const float4*)(bo + hq);
    float4 b_u = *(const float4*)(bu + hq);
    float4 fp = *(const float4*)(Fpart + (long)p * 512 + hq);
    const float* gip = &gi.x; const float* gop = &go.x;
    const float* gup = &gu.x; const float* bip = &b_i.x;
    const float* bop = &b_o.x; const float* bup = &b_u.x;
    const float* fpp = &fp.x;
    float4 hv, cv;
    float* hvp = &hv.x; float* cvp = &cv.x;
#pragma unroll
    for (int j = 0; j < 4; ++j) {
      float iv = sig_(gip[j] + bip[j]);
      float ov = sig_(gop[j] + bop[j]);
      float uv = tanh_(gup[j] + bup[j]);
      float c  = iv * uv + fpp[j];
      cvp[j] = c;
      hvp[j] = ov * tanh_(c);
    }
    *(float4*)(Cv + (long)p * 512 + hq) = cv;
    *(float4*)(&Hl[p * 512 + hq]) = hv;
  }
  __syncthreads();
  if (tid < 128) {
    int hq = tid << 2;
    float4 s = {0.f, 0.f, 0.f, 0.f};
#pragma unroll
    for (int b = 0; b < 16; ++b) {
      float4 v = *(const float4*)(&Hl[b * 512 + hq]);
      s.x += v.x; s.y += v.y; s.z += v.z; s.w += v.w;
    }
    *(ushort4*)(xh + hq) = *(const ushort4*)(xroot + hq);
    ushort4 hw = {f2bf(s.x), f2bf(s.y), f2bf(s.z), f2bf(s.w)};
    *(ushort4*)(xh + 512 + hq) = hw;
  }
}

// ---- fused root tail (r16 verbatim) ----------------------------------------
__global__ void k_root_tail(const float* __restrict__ Fc,
                            const float* __restrict__ Fx,
                            const float* __restrict__ bfb,
                            const float* __restrict__ Cc,
                            const float* __restrict__ G,
                            const float* __restrict__ bi,
                            const float* __restrict__ bo,
                            const float* __restrict__ bu,
                            float* __restrict__ H, float* __restrict__ Cv) {
  int hq = (threadIdx.x & 127) << 2;
  float4 fxv = *(const float4*)(Fx + hq);
  float4 bfv = *(const float4*)(bfb + hq);
  float fx0 = fxv.x + bfv.x, fx1 = fxv.y + bfv.y;
  float fx2 = fxv.z + bfv.z, fx3 = fxv.w + bfv.w;
  float a0 = 0.f, a1 = 0.f, a2 = 0.f, a3 = 0.f;
#pragma unroll 4
  for (int b = 0; b < 16; ++b) {
    float4 f = *(const float4*)(Fc + (long)b * 512 + hq);
    float4 c = *(const float4*)(Cc + (long)b * 512 + hq);
    a0 += sig_(fx0 + f.x) * c.x;
    a1 += sig_(fx1 + f.y) * c.y;
    a2 += sig_(fx2 + f.z) * c.z;
    a3 += sig_(fx3 + f.w) * c.w;
  }
  float fpp[4] = {a0, a1, a2, a3};
  float4 gi = *(const float4*)(G + hq);
  float4 go = *(const float4*)(G + 512 + hq);
  float4 gu = *(const float4*)(G + 1024 + hq);
  float4 b_i = *(const float4*)(bi + hq);
  float4 b_o = *(const float4*)(bo + hq);
  float4 b_u = *(const float4*)(bu + hq);
  const float* gip = &gi.x; const float* gop = &go.x; const float* gup = &gu.x;
  const float* bip = &b_i.x; const float* bop = &b_o.x; const float* bup = &b_u.x;
  float4 hv, cv;
  float* hvp = &hv.x; float* cvp = &cv.x;
#pragma unroll
  for (int j = 0; j < 4; ++j) {
    float iv = sig_(gip[j] + bip[j]);
    float ov = sig_(gop[j] + bop[j]);
    float uv = tanh_(gup[j] + bup[j]);
    float c  = iv * uv + fpp[j];
    cvp[j] = c;
    hvp[j] = ov * tanh_(c);
  }
  *(float4*)(H  + hq) = hv;
  *(float4*)(Cv + hq) = cv;
}

// ---------------------------------------------------------------------------
extern "C" void kernel_launch(void* const* d_in, const int* in_sizes, int n_in,
                              void* d_out, int out_size, void* d_ws, size_t ws_size,
                              hipStream_t stream) {
  const float* x    = (const float*)d_in[0];
  const float* wi_w = (const float*)d_in[1];
  const float* wi_b = (const float*)d_in[2];
  const float* wf_w = (const float*)d_in[3];
  const float* wf_b = (const float*)d_in[4];
  const float* wo_w = (const float*)d_in[5];
  const float* wo_b = (const float*)d_in[6];
  const float* wu_w = (const float*)d_in[7];
  const float* wu_b = (const float*)d_in[8];
  (void)in_sizes; (void)n_in; (void)out_size; (void)ws_size;

  static const long offs[5] = {0, 1, 17, 273, 4369};
  const long NTOT = 69905;

  // ---- workspace ----
  char* ws = (char*)d_ws;
  size_t off = 0;
  auto alloc = [&](size_t bytes) -> void* {
    void* p = ws + off;
    off += (bytes + 255) & ~(size_t)255;
    return p;
  };
  uint16_t* Xbf   = (uint16_t*)alloc(NTOT * 512 * 2);
  uint16_t* Wgw   = (uint16_t*)alloc((size_t)2048 * 1024 * 2);
  uint16_t* Wg    = Wgw;
  uint16_t* Wf    = Wgw + (size_t)1536 * 1024;
  float*    FxAll = (float*)alloc((size_t)4480 * 512 * 4);
  uint16_t* Cbf   = (uint16_t*)alloc((size_t)65536 * 512 * 2);
  uint16_t* CbfU  = (uint16_t*)alloc((size_t)4096 * 512 * 2);
  uint16_t* CbfU2 = (uint16_t*)alloc((size_t)256 * 512 * 2);
  uint16_t* xhA   = (uint16_t*)alloc((size_t)4096 * 1024 * 2);
  uint16_t* xhB   = (uint16_t*)alloc((size_t)256 * 1024 * 2);
  uint16_t* xhC   = (uint16_t*)alloc((size_t)16 * 1024 * 2);
  float*    Fpart = (float*)alloc((size_t)4096 * 512 * 4);
  float*    G3    = (float*)alloc((size_t)4096 * 1536 * 4);
  float*    Gf    = (float*)alloc((size_t)16 * 1536 * 4);
  float*    Fc    = (float*)alloc((size_t)16 * 512 * 4);
  float*    CupA  = (float*)alloc((size_t)16 * 512 * 4);

  // ---- merged convert: all x + 4 weight matrices ----
  {
    long n4x = NTOT * 512 / 4;
    k_conv_all<<<8192, 256, 0, stream>>>(
        (const float4*)x, (ushort4*)Xbf, n4x,
        (const float4*)wi_w, (const float4*)wo_w,
        (const float4*)wu_w, (const float4*)wf_w, (ushort4*)Wgw);
  }

  // ---- leaf level + FxAll gemm in ONE launch (4096 + 140 blocks) ----
  k_leaf_fx<<<4236, 256, 0, stream>>>(
      Xbf + offs[4] * 512, Wg, wi_b, wo_b, wu_b,
      Cbf, Xbf + offs[3] * 512, xhA,
      Xbf, Wf, FxAll);

  // ---- leaf fc (2048) || lvl3 gates (512) in ONE launch ----
  k_fc4_l3g<<<2560, 256, 0, stream>>>(
      Cbf, Wf + 512, FxAll + offs[3] * 512, wf_b, Fpart,
      xhA, Wg, G3);

  // ---- lvl3 final: gates+Fpart -> CbfU, xhB (256 parents) ----
  k_level_final<<<256, 128, 0, stream>>>(
      G3, Fpart, wi_b, wo_b, wu_b, CbfU, Xbf + offs[2] * 512, xhB);

  // ---- lvl3 fc (256) || lvl2 gates (32) in ONE launch ----
  k_fc2_l2g<<<288, 256, 0, stream>>>(
      CbfU, Wf + 512, FxAll + offs[2] * 512, wf_b, Fpart,
      xhB, Wg, G3);

  // ---- lvl2 final: gates+Fpart -> CbfU2, xhC (16 parents) ----
  k_level_final<<<16, 128, 0, stream>>>(
      G3, Fpart, wi_b, wo_b, wu_b, CbfU2, Xbf + offs[1] * 512, xhC);

  // ---- lvl2 fc + lvl1 gate dots in ONE launch (16 + 6144 blocks) ----
  k_fcdot<<<6160, 256, 0, stream>>>(CbfU2, Wf + 512,
                                    FxAll + offs[1] * 512, wf_b, Fpart,
                                    xhC, Wg, Gf);

  // ---- level 1 tail (final + hsum + root pack) ----
  k_lvl1_tail<<<1, 1024, 0, stream>>>(Gf, Fpart, wi_b, wo_b, wu_b,
                                      CupA, Xbf + offs[0] * 512, xhC);

  // ---- level 0 (root): merged gate-dot + Fc-dot, then fused tail ----
  {
    long waves = 1536 + 16L * 512;       // 9728 waves = 2432 blocks exactly
    k_dot_merge<<<(int)(waves / 4), 256, 0, stream>>>(
        xhC, Wg, Gf, CupA, wf_w + 512, Fc);
  }
  k_root_tail<<<1, 128, 0, stream>>>(Fc, FxAll, wf_b, CupA, Gf,
                                     wi_b, wo_b, wu_b,
                                     (float*)d_out, (float*)d_out + 512);
}